// Round 2
// baseline (410.162 us; speedup 1.0000x reference)
//
#include <hip/hip_runtime.h>

#define NP 8732
#define NO 16
#define BLK 512
#define NWAVE (BLK / 64)

// One block per batch row: match priors<->boxes (division-free IoU compares),
// CE for all priors, loc L1 for positives, hard-negative top-K via LDS
// radix-select with ballot-aggregated histograms and early exit.
__global__ __launch_bounds__(BLK, 4) void mbox_row_kernel(
    const float* __restrict__ plocs,    // [B,P,4]
    const float* __restrict__ pscores,  // [B,P,2]
    const float* __restrict__ boxes,    // [B,O,4] cxcy
    const float* __restrict__ priors,   // [P,4]  cxcy
    float* __restrict__ loc_out,        // [B]
    float* __restrict__ conf_out,       // [B]
    int*   __restrict__ npos_out)       // [B]
{
    const int b    = blockIdx.x;
    const int tid  = threadIdx.x;
    const int lane = tid & 63;
    const int wv   = tid >> 6;

    __shared__ float         s_ce[NP];        // ce_neg values (phase C/D)
    __shared__ unsigned char s_obj[NP];       // bit7 = pos, bits3:0 = obj
    __shared__ float s_bcw[NO][4];            // boxes cxcy
    __shared__ float s_bxy[NO][4];            // boxes corners
    __shared__ float s_barea[NO];
    __shared__ float s_redn[NO * NWAVE];      // per-object argmax: numerator
    __shared__ float s_redd[NO * NWAVE];      //                    denominator
    __shared__ int   s_redi[NO * NWAVE];      //                    prior idx
    __shared__ int   s_bestp[NO];
    __shared__ unsigned int s_hist[16];
    __shared__ unsigned int s_state[3];       // prefix, k, chosen-bin count
    __shared__ float s_tval;
    __shared__ float s_fred[3 * NWAVE];
    __shared__ int   s_ired[NWAVE];

    // ---- load boxes, precompute corners & areas ----
    if (tid < NO * 4) ((float*)s_bcw)[tid] = boxes[(size_t)b * NO * 4 + tid];
    __syncthreads();
    if (tid < NO) {
        float cx = s_bcw[tid][0], cy = s_bcw[tid][1];
        float w  = s_bcw[tid][2], h  = s_bcw[tid][3];
        float x0 = cx - w * 0.5f, y0 = cy - h * 0.5f;
        float x1 = cx + w * 0.5f, y1 = cy + h * 0.5f;
        s_bxy[tid][0] = x0; s_bxy[tid][1] = y0;
        s_bxy[tid][2] = x1; s_bxy[tid][3] = y1;
        s_barea[tid] = (x1 - x0) * (y1 - y0);
    }
    __syncthreads();

    // ---- phase A: IoU matching, all comparisons via cross-multiplication ----
    float bio[NO], bdo[NO]; int bpo[NO];   // per-object best (inter, den, prior)
#pragma unroll
    for (int o = 0; o < NO; o++) { bio[o] = 0.0f; bdo[o] = 1.0f; bpo[o] = tid; }

    for (int p = tid; p < NP; p += BLK) {
        float4 pr = ((const float4*)priors)[p];
        float px0 = pr.x - pr.z * 0.5f, py0 = pr.y - pr.w * 0.5f;
        float px1 = pr.x + pr.z * 0.5f, py1 = pr.y + pr.w * 0.5f;
        float areab = (px1 - px0) * (py1 - py0);
        float bi = 0.0f, bd = 1.0f; int bo = 0;   // best over objects
#pragma unroll
        for (int o = 0; o < NO; o++) {
            float ix0 = fmaxf(s_bxy[o][0], px0);
            float iy0 = fmaxf(s_bxy[o][1], py0);
            float ix1 = fminf(s_bxy[o][2], px1);
            float iy1 = fminf(s_bxy[o][3], py1);
            float iw = fmaxf(ix1 - ix0, 0.0f);
            float ih = fmaxf(iy1 - iy0, 0.0f);
            float inter = iw * ih;
            float den = s_barea[o] + areab - inter;
            // iou > best  <=>  inter*bd > bi*den   (first-wins over o)
            if (inter * bd > bi * den) { bi = inter; bd = den; bo = o; }
            // per-object best over p (ascending p => first-wins)
            if (inter * bdo[o] > bio[o] * den) { bio[o] = inter; bdo[o] = den; bpo[o] = p; }
        }
        bool pos = (2.0f * bi >= bd);            // iou >= 0.5
        s_obj[p] = (unsigned char)(bo | (pos ? 0x80 : 0));
    }

    // reduce per-object best prior across block (larger value, then smaller idx)
#pragma unroll
    for (int o = 0; o < NO; o++) {
        float n = bio[o], d = bdo[o]; int i = bpo[o];
        for (int off = 32; off; off >>= 1) {
            float n2 = __shfl_down(n, off, 64);
            float d2 = __shfl_down(d, off, 64);
            int   i2 = __shfl_down(i, off, 64);
            float a = n2 * d, c = n * d2;
            if (a > c || (a == c && i2 < i)) { n = n2; d = d2; i = i2; }
        }
        if (lane == 0) {
            s_redn[o * NWAVE + wv] = n;
            s_redd[o * NWAVE + wv] = d;
            s_redi[o * NWAVE + wv] = i;
        }
    }
    __syncthreads();
    if (tid < NO) {
        float n = s_redn[tid * NWAVE], d = s_redd[tid * NWAVE];
        int i = s_redi[tid * NWAVE];
#pragma unroll
        for (int w = 1; w < NWAVE; w++) {
            float n2 = s_redn[tid * NWAVE + w], d2 = s_redd[tid * NWAVE + w];
            int i2 = s_redi[tid * NWAVE + w];
            float a = n2 * d, c = n * d2;
            if (a > c || (a == c && i2 < i)) { n = n2; d = d2; i = i2; }
        }
        s_bestp[tid] = i;
    }
    __syncthreads();
    // forced assignment (serial ascending: last o wins on duplicate priors)
    if (tid == 0) {
#pragma unroll
        for (int o = 0; o < NO; o++) s_obj[s_bestp[o]] = (unsigned char)(0x80 | o);
    }
    __syncthreads();

    // ---- phase C: CE for all priors, loc L1 for positives ----
    float loc_sum = 0.0f, conf_pos = 0.0f; int np = 0;
    const float2* sc2 = (const float2*)(pscores + (size_t)b * NP * 2);
    const float4* pl4 = (const float4*)(plocs  + (size_t)b * NP * 4);
    for (int p = tid; p < NP; p += BLK) {
        unsigned m = s_obj[p];
        bool pos = (m & 0x80) != 0;
        float2 s = sc2[p];
        float mx = fmaxf(s.x, s.y);
        float dd = fabsf(s.x - s.y);
        float lse = mx + __logf(1.0f + __expf(-dd));
        float ce = lse - (pos ? s.y : s.x);
        if (pos) {
            np++;
            conf_pos += ce;
            int o = m & 15;
            float4 pr = ((const float4*)priors)[p];
            float gx = (s_bcw[o][0] - pr.x) / (pr.z / 10.0f);
            float gy = (s_bcw[o][1] - pr.y) / (pr.w / 10.0f);
            float gw = __logf(s_bcw[o][2] / pr.z) * 5.0f;
            float gh = __logf(s_bcw[o][3] / pr.w) * 5.0f;
            float4 pl = pl4[p];
            loc_sum += fabsf(pl.x - gx) + fabsf(pl.y - gy)
                     + fabsf(pl.z - gw) + fabsf(pl.w - gh);
            s_ce[p] = 0.0f;
        } else {
            s_ce[p] = ce;
        }
    }

    // n_pos reduction (need K before select)
    int npw = np;
    for (int off = 32; off; off >>= 1) npw += __shfl_down(npw, off, 64);
    if (lane == 0) s_ired[wv] = npw;
    __syncthreads();
    int n_pos = 0;
#pragma unroll
    for (int w = 0; w < NWAVE; w++) n_pos += s_ired[w];

    // ---- phase D: radix-select K-th largest of s_ce (values >= 0) ----
    const int K = 3 * n_pos;
    const bool selAll = (K >= NP);
    float t = 0.0f;
    if (!selAll) {
        if (tid == 0) { s_state[0] = 0u; s_state[1] = (unsigned)K; s_state[2] = 0u; }
        bool done = false;
        for (int shift = 28; shift >= 0 && !done; shift -= 4) {
            __syncthreads();
            if (tid < 16) s_hist[tid] = 0u;
            __syncthreads();
            unsigned prefix = s_state[0];
            unsigned maskhi = (shift == 28) ? 0u : (0xFFFFFFFFu << (shift + 4));
            for (int p = tid; p < NP; p += BLK) {
                unsigned u = __float_as_uint(s_ce[p]);
                unsigned d = ((u & maskhi) == prefix) ? ((u >> shift) & 15u) : 31u;
                unsigned long long mm = __ballot(1);   // active lanes
#pragma unroll
                for (int bit = 0; bit < 5; bit++) {
                    unsigned long long bl = __ballot((d >> bit) & 1u);
                    mm &= ((d >> bit) & 1u) ? bl : ~bl;
                }
                int leader = __ffsll(mm) - 1;
                if (lane == leader && d < 16u)
                    atomicAdd(&s_hist[d], (unsigned)__popcll(mm));
            }
            __syncthreads();
            if (tid == 0) {
                unsigned kk = s_state[1];
                int dsel = 15;
                for (; dsel > 0; dsel--) { unsigned h = s_hist[dsel]; if (kk <= h) break; kk -= h; }
                s_state[0] = prefix | ((unsigned)dsel << shift);
                s_state[1] = kk;
                s_state[2] = s_hist[dsel];
            }
            __syncthreads();
            if (shift > 0 && s_state[2] == 1u) {
                // unique survivor: fetch it, done
                unsigned pfx = s_state[0];
                unsigned mh  = 0xFFFFFFFFu << shift;
                for (int p = tid; p < NP; p += BLK) {
                    unsigned u = __float_as_uint(s_ce[p]);
                    if ((u & mh) == pfx) s_tval = s_ce[p];
                }
                __syncthreads();
                t = s_tval;
                done = true;
            } else if (shift == 0) {
                t = __uint_as_float(s_state[0]);
            }
        }
        if (!done) t = __uint_as_float(s_state[0]);
    }

    // sum of top-K = sum(v > t) + (K - cnt_gt) * t   (exact under ties)
    float sgt = 0.0f; int cgt = 0;
    for (int p = tid; p < NP; p += BLK) {
        float v = s_ce[p];
        if (selAll || v > t) { sgt += v; cgt++; }
    }

    // ---- final block reduction of (sgt, conf_pos, loc_sum, cgt) ----
    float a = sgt, c = conf_pos, l = loc_sum; int g = cgt;
    for (int off = 32; off; off >>= 1) {
        a += __shfl_down(a, off, 64);
        c += __shfl_down(c, off, 64);
        l += __shfl_down(l, off, 64);
        g += __shfl_down(g, off, 64);
    }
    __syncthreads();
    if (lane == 0) {
        s_fred[wv] = a; s_fred[NWAVE + wv] = c; s_fred[2 * NWAVE + wv] = l;
        s_ired[wv] = g;
    }
    __syncthreads();
    if (tid == 0) {
        float sa = 0.0f, sc = 0.0f, sl = 0.0f; int sg = 0;
#pragma unroll
        for (int w = 0; w < NWAVE; w++) {
            sa += s_fred[w]; sc += s_fred[NWAVE + w]; sl += s_fred[2 * NWAVE + w];
            sg += s_ired[w];
        }
        float conf_hn = selAll ? sa : (sa + (float)(K - sg) * t);
        conf_out[b] = sc + conf_hn;
        loc_out[b]  = sl;
        npos_out[b] = n_pos;
    }
}

__global__ __launch_bounds__(256) void mbox_finalize_kernel(
    const float* __restrict__ loc_in,
    const float* __restrict__ conf_in,
    const int*   __restrict__ npos_in,
    int B, float* __restrict__ out)
{
    __shared__ float sl[4], sc[4];
    __shared__ int   si[4];
    int tid = threadIdx.x, lane = tid & 63, wv = tid >> 6;
    float l = 0.0f, c = 0.0f; int n = 0;
    for (int i = tid; i < B; i += 256) { l += loc_in[i]; c += conf_in[i]; n += npos_in[i]; }
    for (int off = 32; off; off >>= 1) {
        l += __shfl_down(l, off, 64);
        c += __shfl_down(c, off, 64);
        n += __shfl_down(n, off, 64);
    }
    if (lane == 0) { sl[wv] = l; sc[wv] = c; si[wv] = n; }
    __syncthreads();
    if (tid == 0) {
        float tl = sl[0] + sl[1] + sl[2] + sl[3];
        float tc = sc[0] + sc[1] + sc[2] + sc[3];
        int   tn = si[0] + si[1] + si[2] + si[3];
        float fn = (float)tn;
        out[0] = tc / fn + tl / (fn * 4.0f);
    }
}

extern "C" void kernel_launch(void* const* d_in, const int* in_sizes, int n_in,
                              void* d_out, int out_size, void* d_ws, size_t ws_size,
                              hipStream_t stream) {
    const float* plocs   = (const float*)d_in[0];
    const float* pscores = (const float*)d_in[1];
    const float* boxes   = (const float*)d_in[2];
    const float* priors  = (const float*)d_in[3];
    const int B = in_sizes[0] / (NP * 4);

    float* loc_ws  = (float*)d_ws;
    float* conf_ws = loc_ws + B;
    int*   np_ws   = (int*)(conf_ws + B);

    mbox_row_kernel<<<B, BLK, 0, stream>>>(plocs, pscores, boxes, priors,
                                           loc_ws, conf_ws, np_ws);
    mbox_finalize_kernel<<<1, 256, 0, stream>>>(loc_ws, conf_ws, np_ws, B, (float*)d_out);
}

// Round 3
// 275.929 us; speedup vs baseline: 1.4865x; 1.4865x over previous
//
#include <hip/hip_runtime.h>

#define NP 8732
#define NO 16
#define BLK 512
#define NWAVE (BLK / 64)

// One block per batch row: match priors<->boxes (division-free IoU compares),
// CE for all priors, loc L1 for positives, hard-negative top-K via LDS
// radix-select with ballot-aggregated histograms and early exit.
// NOTE: __launch_bounds__ min-waves arg MUST stay <=2: the ",4" variant made
// the allocator clamp to 64 VGPRs and spill the per-object tracking arrays
// (192 B/thread scratch -> 52 MB writes, 445 MB fetch, 2.3x slower).
__global__ __launch_bounds__(BLK, 2) void mbox_row_kernel(
    const float* __restrict__ plocs,    // [B,P,4]
    const float* __restrict__ pscores,  // [B,P,2]
    const float* __restrict__ boxes,    // [B,O,4] cxcy
    const float* __restrict__ priors,   // [P,4]  cxcy
    float* __restrict__ loc_out,        // [B]
    float* __restrict__ conf_out,       // [B]
    int*   __restrict__ npos_out)       // [B]
{
    const int b    = blockIdx.x;
    const int tid  = threadIdx.x;
    const int lane = tid & 63;
    const int wv   = tid >> 6;

    __shared__ float         s_ce[NP];        // ce_neg values (phase C/D)
    __shared__ unsigned char s_obj[NP];       // bit7 = pos, bits3:0 = obj
    __shared__ float s_bcw[NO][4];            // boxes cxcy
    __shared__ float s_bxy[NO][4];            // boxes corners
    __shared__ float s_barea[NO];
    __shared__ float s_redn[NO * NWAVE];      // per-object argmax: numerator
    __shared__ float s_redd[NO * NWAVE];      //                    denominator
    __shared__ int   s_redi[NO * NWAVE];      //                    prior idx
    __shared__ int   s_bestp[NO];
    __shared__ unsigned int s_hist[16];
    __shared__ unsigned int s_state[3];       // prefix, k, chosen-bin count
    __shared__ float s_tval;
    __shared__ float s_fred[3 * NWAVE];
    __shared__ int   s_ired[NWAVE];

    // ---- load boxes, precompute corners & areas ----
    if (tid < NO * 4) ((float*)s_bcw)[tid] = boxes[(size_t)b * NO * 4 + tid];
    __syncthreads();
    if (tid < NO) {
        float cx = s_bcw[tid][0], cy = s_bcw[tid][1];
        float w  = s_bcw[tid][2], h  = s_bcw[tid][3];
        float x0 = cx - w * 0.5f, y0 = cy - h * 0.5f;
        float x1 = cx + w * 0.5f, y1 = cy + h * 0.5f;
        s_bxy[tid][0] = x0; s_bxy[tid][1] = y0;
        s_bxy[tid][2] = x1; s_bxy[tid][3] = y1;
        s_barea[tid] = (x1 - x0) * (y1 - y0);
    }
    __syncthreads();

    // ---- phase A: IoU matching, all comparisons via cross-multiplication ----
    float bio[NO], bdo[NO]; int bpo[NO];   // per-object best (inter, den, prior)
#pragma unroll
    for (int o = 0; o < NO; o++) { bio[o] = 0.0f; bdo[o] = 1.0f; bpo[o] = tid; }

    for (int p = tid; p < NP; p += BLK) {
        float4 pr = ((const float4*)priors)[p];
        float px0 = pr.x - pr.z * 0.5f, py0 = pr.y - pr.w * 0.5f;
        float px1 = pr.x + pr.z * 0.5f, py1 = pr.y + pr.w * 0.5f;
        float areab = (px1 - px0) * (py1 - py0);
        float bi = 0.0f, bd = 1.0f; int bo = 0;   // best over objects
#pragma unroll
        for (int o = 0; o < NO; o++) {
            float ix0 = fmaxf(s_bxy[o][0], px0);
            float iy0 = fmaxf(s_bxy[o][1], py0);
            float ix1 = fminf(s_bxy[o][2], px1);
            float iy1 = fminf(s_bxy[o][3], py1);
            float iw = fmaxf(ix1 - ix0, 0.0f);
            float ih = fmaxf(iy1 - iy0, 0.0f);
            float inter = iw * ih;
            float den = s_barea[o] + areab - inter;
            // iou > best  <=>  inter*bd > bi*den   (first-wins over o)
            if (inter * bd > bi * den) { bi = inter; bd = den; bo = o; }
            // per-object best over p (ascending p => first-wins)
            if (inter * bdo[o] > bio[o] * den) { bio[o] = inter; bdo[o] = den; bpo[o] = p; }
        }
        bool pos = (2.0f * bi >= bd);            // iou >= 0.5
        s_obj[p] = (unsigned char)(bo | (pos ? 0x80 : 0));
    }

    // reduce per-object best prior across block (larger value, then smaller idx)
#pragma unroll
    for (int o = 0; o < NO; o++) {
        float n = bio[o], d = bdo[o]; int i = bpo[o];
        for (int off = 32; off; off >>= 1) {
            float n2 = __shfl_down(n, off, 64);
            float d2 = __shfl_down(d, off, 64);
            int   i2 = __shfl_down(i, off, 64);
            float a = n2 * d, c = n * d2;
            if (a > c || (a == c && i2 < i)) { n = n2; d = d2; i = i2; }
        }
        if (lane == 0) {
            s_redn[o * NWAVE + wv] = n;
            s_redd[o * NWAVE + wv] = d;
            s_redi[o * NWAVE + wv] = i;
        }
    }
    __syncthreads();
    if (tid < NO) {
        float n = s_redn[tid * NWAVE], d = s_redd[tid * NWAVE];
        int i = s_redi[tid * NWAVE];
#pragma unroll
        for (int w = 1; w < NWAVE; w++) {
            float n2 = s_redn[tid * NWAVE + w], d2 = s_redd[tid * NWAVE + w];
            int i2 = s_redi[tid * NWAVE + w];
            float a = n2 * d, c = n * d2;
            if (a > c || (a == c && i2 < i)) { n = n2; d = d2; i = i2; }
        }
        s_bestp[tid] = i;
    }
    __syncthreads();
    // forced assignment (serial ascending: last o wins on duplicate priors)
    if (tid == 0) {
#pragma unroll
        for (int o = 0; o < NO; o++) s_obj[s_bestp[o]] = (unsigned char)(0x80 | o);
    }
    __syncthreads();

    // ---- phase C: CE for all priors, loc L1 for positives ----
    float loc_sum = 0.0f, conf_pos = 0.0f; int np = 0;
    const float2* sc2 = (const float2*)(pscores + (size_t)b * NP * 2);
    const float4* pl4 = (const float4*)(plocs  + (size_t)b * NP * 4);
    for (int p = tid; p < NP; p += BLK) {
        unsigned m = s_obj[p];
        bool pos = (m & 0x80) != 0;
        float2 s = sc2[p];
        float mx = fmaxf(s.x, s.y);
        float dd = fabsf(s.x - s.y);
        float lse = mx + __logf(1.0f + __expf(-dd));
        float ce = lse - (pos ? s.y : s.x);
        if (pos) {
            np++;
            conf_pos += ce;
            int o = m & 15;
            float4 pr = ((const float4*)priors)[p];
            float gx = (s_bcw[o][0] - pr.x) / (pr.z / 10.0f);
            float gy = (s_bcw[o][1] - pr.y) / (pr.w / 10.0f);
            float gw = __logf(s_bcw[o][2] / pr.z) * 5.0f;
            float gh = __logf(s_bcw[o][3] / pr.w) * 5.0f;
            float4 pl = pl4[p];
            loc_sum += fabsf(pl.x - gx) + fabsf(pl.y - gy)
                     + fabsf(pl.z - gw) + fabsf(pl.w - gh);
            s_ce[p] = 0.0f;
        } else {
            s_ce[p] = ce;
        }
    }

    // n_pos reduction (need K before select)
    int npw = np;
    for (int off = 32; off; off >>= 1) npw += __shfl_down(npw, off, 64);
    if (lane == 0) s_ired[wv] = npw;
    __syncthreads();
    int n_pos = 0;
#pragma unroll
    for (int w = 0; w < NWAVE; w++) n_pos += s_ired[w];

    // ---- phase D: radix-select K-th largest of s_ce (values >= 0) ----
    const int K = 3 * n_pos;
    const bool selAll = (K >= NP);
    float t = 0.0f;
    if (!selAll) {
        if (tid == 0) { s_state[0] = 0u; s_state[1] = (unsigned)K; s_state[2] = 0u; }
        bool done = false;
        for (int shift = 28; shift >= 0 && !done; shift -= 4) {
            __syncthreads();
            if (tid < 16) s_hist[tid] = 0u;
            __syncthreads();
            unsigned prefix = s_state[0];
            unsigned maskhi = (shift == 28) ? 0u : (0xFFFFFFFFu << (shift + 4));
            for (int p = tid; p < NP; p += BLK) {
                unsigned u = __float_as_uint(s_ce[p]);
                unsigned d = ((u & maskhi) == prefix) ? ((u >> shift) & 15u) : 31u;
                unsigned long long mm = __ballot(1);   // active lanes
#pragma unroll
                for (int bit = 0; bit < 5; bit++) {
                    unsigned long long bl = __ballot((d >> bit) & 1u);
                    mm &= ((d >> bit) & 1u) ? bl : ~bl;
                }
                int leader = __ffsll(mm) - 1;
                if (lane == leader && d < 16u)
                    atomicAdd(&s_hist[d], (unsigned)__popcll(mm));
            }
            __syncthreads();
            if (tid == 0) {
                unsigned kk = s_state[1];
                int dsel = 15;
                for (; dsel > 0; dsel--) { unsigned h = s_hist[dsel]; if (kk <= h) break; kk -= h; }
                s_state[0] = prefix | ((unsigned)dsel << shift);
                s_state[1] = kk;
                s_state[2] = s_hist[dsel];
            }
            __syncthreads();
            if (shift > 0 && s_state[2] == 1u) {
                // unique survivor: fetch it, done
                unsigned pfx = s_state[0];
                unsigned mh  = 0xFFFFFFFFu << shift;
                for (int p = tid; p < NP; p += BLK) {
                    unsigned u = __float_as_uint(s_ce[p]);
                    if ((u & mh) == pfx) s_tval = s_ce[p];
                }
                __syncthreads();
                t = s_tval;
                done = true;
            } else if (shift == 0) {
                t = __uint_as_float(s_state[0]);
            }
        }
        if (!done) t = __uint_as_float(s_state[0]);
    }

    // sum of top-K = sum(v > t) + (K - cnt_gt) * t   (exact under ties)
    float sgt = 0.0f; int cgt = 0;
    for (int p = tid; p < NP; p += BLK) {
        float v = s_ce[p];
        if (selAll || v > t) { sgt += v; cgt++; }
    }

    // ---- final block reduction of (sgt, conf_pos, loc_sum, cgt) ----
    float a = sgt, c = conf_pos, l = loc_sum; int g = cgt;
    for (int off = 32; off; off >>= 1) {
        a += __shfl_down(a, off, 64);
        c += __shfl_down(c, off, 64);
        l += __shfl_down(l, off, 64);
        g += __shfl_down(g, off, 64);
    }
    __syncthreads();
    if (lane == 0) {
        s_fred[wv] = a; s_fred[NWAVE + wv] = c; s_fred[2 * NWAVE + wv] = l;
        s_ired[wv] = g;
    }
    __syncthreads();
    if (tid == 0) {
        float sa = 0.0f, sc = 0.0f, sl = 0.0f; int sg = 0;
#pragma unroll
        for (int w = 0; w < NWAVE; w++) {
            sa += s_fred[w]; sc += s_fred[NWAVE + w]; sl += s_fred[2 * NWAVE + w];
            sg += s_ired[w];
        }
        float conf_hn = selAll ? sa : (sa + (float)(K - sg) * t);
        conf_out[b] = sc + conf_hn;
        loc_out[b]  = sl;
        npos_out[b] = n_pos;
    }
}

__global__ __launch_bounds__(256) void mbox_finalize_kernel(
    const float* __restrict__ loc_in,
    const float* __restrict__ conf_in,
    const int*   __restrict__ npos_in,
    int B, float* __restrict__ out)
{
    __shared__ float sl[4], sc[4];
    __shared__ int   si[4];
    int tid = threadIdx.x, lane = tid & 63, wv = tid >> 6;
    float l = 0.0f, c = 0.0f; int n = 0;
    for (int i = tid; i < B; i += 256) { l += loc_in[i]; c += conf_in[i]; n += npos_in[i]; }
    for (int off = 32; off; off >>= 1) {
        l += __shfl_down(l, off, 64);
        c += __shfl_down(c, off, 64);
        n += __shfl_down(n, off, 64);
    }
    if (lane == 0) { sl[wv] = l; sc[wv] = c; si[wv] = n; }
    __syncthreads();
    if (tid == 0) {
        float tl = sl[0] + sl[1] + sl[2] + sl[3];
        float tc = sc[0] + sc[1] + sc[2] + sc[3];
        int   tn = si[0] + si[1] + si[2] + si[3];
        float fn = (float)tn;
        out[0] = tc / fn + tl / (fn * 4.0f);
    }
}

extern "C" void kernel_launch(void* const* d_in, const int* in_sizes, int n_in,
                              void* d_out, int out_size, void* d_ws, size_t ws_size,
                              hipStream_t stream) {
    const float* plocs   = (const float*)d_in[0];
    const float* pscores = (const float*)d_in[1];
    const float* boxes   = (const float*)d_in[2];
    const float* priors  = (const float*)d_in[3];
    const int B = in_sizes[0] / (NP * 4);

    float* loc_ws  = (float*)d_ws;
    float* conf_ws = loc_ws + B;
    int*   np_ws   = (int*)(conf_ws + B);

    mbox_row_kernel<<<B, BLK, 0, stream>>>(plocs, pscores, boxes, priors,
                                           loc_ws, conf_ws, np_ws);
    mbox_finalize_kernel<<<1, 256, 0, stream>>>(loc_ws, conf_ws, np_ws, B, (float*)d_out);
}

// Round 4
// 243.299 us; speedup vs baseline: 1.6858x; 1.1341x over previous
//
#include <hip/hip_runtime.h>

#define NP 8732
#define NQ (NP / 4)          // 2183 float4 chunks (NP divisible by 4)
#define NO 16
#define BLK 256
#define NWAVE (BLK / 64)

// One block per batch row. BLK=256 beats 512 (fewer waves idling at the
// per-block barriers/serial sections: 136us vs 177us measured).
// __launch_bounds__ min-waves must stay <=2: ",4" clamped VGPRs to 64 and
// spilled the per-object tracking arrays (52MB scratch writes, 2.3x slower).
__global__ __launch_bounds__(BLK, 2) void mbox_row_kernel(
    const float* __restrict__ plocs,    // [B,P,4]
    const float* __restrict__ pscores,  // [B,P,2]
    const float* __restrict__ boxes,    // [B,O,4] cxcy
    const float* __restrict__ priors,   // [P,4]  cxcy
    float* __restrict__ loc_out,        // [B]
    float* __restrict__ conf_out,       // [B]
    int*   __restrict__ npos_out)       // [B]
{
    const int b    = blockIdx.x;
    const int tid  = threadIdx.x;
    const int lane = tid & 63;
    const int wv   = tid >> 6;

    __shared__ __align__(16) float s_ce[NP];  // ce_neg values (phase C/D)
    __shared__ unsigned char s_obj[NP];       // bit7 = pos, bits3:0 = obj
    __shared__ float s_bcw[NO][4];            // boxes cxcy
    __shared__ float s_bxy[NO][4];            // boxes corners
    __shared__ float s_barea[NO];
    __shared__ float s_redn[NO * NWAVE];      // per-object argmax: numerator
    __shared__ float s_redd[NO * NWAVE];      //                    denominator
    __shared__ int   s_redi[NO * NWAVE];      //                    prior idx
    __shared__ int   s_bestp[NO];
    __shared__ unsigned int s_hist[16];
    __shared__ float s_tval;
    __shared__ float s_fred[3 * NWAVE];
    __shared__ int   s_ired[NWAVE];

    // ---- load boxes, precompute corners & areas ----
    if (tid < NO * 4) ((float*)s_bcw)[tid] = boxes[(size_t)b * NO * 4 + tid];
    __syncthreads();
    if (tid < NO) {
        float cx = s_bcw[tid][0], cy = s_bcw[tid][1];
        float w  = s_bcw[tid][2], h  = s_bcw[tid][3];
        float x0 = cx - w * 0.5f, y0 = cy - h * 0.5f;
        float x1 = cx + w * 0.5f, y1 = cy + h * 0.5f;
        s_bxy[tid][0] = x0; s_bxy[tid][1] = y0;
        s_bxy[tid][2] = x1; s_bxy[tid][3] = y1;
        s_barea[tid] = (x1 - x0) * (y1 - y0);
    }
    __syncthreads();

    // ---- register-cache all 16 boxes (kills ~80 LDS reads per p-iteration,
    //      which were the phase-A latency stall: VGPR 84 in the LDS version
    //      proved the compiler never hoisted them) ----
    float rx0[NO], ry0[NO], rx1[NO], ry1[NO], ra[NO];
#pragma unroll
    for (int o = 0; o < NO; o++) {
        rx0[o] = s_bxy[o][0]; ry0[o] = s_bxy[o][1];
        rx1[o] = s_bxy[o][2]; ry1[o] = s_bxy[o][3];
        ra[o]  = s_barea[o];
    }

    // ---- phase A: IoU matching, division-free comparisons ----
    float bio[NO], bdo[NO]; int bpo[NO];   // per-object best (inter, den, prior)
#pragma unroll
    for (int o = 0; o < NO; o++) { bio[o] = 0.0f; bdo[o] = 1.0f; bpo[o] = 0; }

    for (int p = tid; p < NP; p += BLK) {
        float4 pr = ((const float4*)priors)[p];
        float px0 = pr.x - pr.z * 0.5f, py0 = pr.y - pr.w * 0.5f;
        float px1 = pr.x + pr.z * 0.5f, py1 = pr.y + pr.w * 0.5f;
        float areab = (px1 - px0) * (py1 - py0);
        float bi = 0.0f, bd = 1.0f; int bo = 0;   // best over objects
#pragma unroll
        for (int o = 0; o < NO; o++) {
            float ix0 = fmaxf(rx0[o], px0);
            float iy0 = fmaxf(ry0[o], py0);
            float ix1 = fminf(rx1[o], px1);
            float iy1 = fminf(ry1[o], py1);
            float iw = fmaxf(ix1 - ix0, 0.0f);
            float ih = fmaxf(iy1 - iy0, 0.0f);
            float inter = iw * ih;
            float den = ra[o] + areab - inter;
            // iou > best  <=>  inter*bd > bi*den   (first-wins over o)
            if (inter * bd > bi * den) { bi = inter; bd = den; bo = o; }
            // per-object best over p (ascending p => first-wins)
            if (inter * bdo[o] > bio[o] * den) { bio[o] = inter; bdo[o] = den; bpo[o] = p; }
        }
        bool pos = (2.0f * bi >= bd);            // iou >= 0.5
        s_obj[p] = (unsigned char)(bo | (pos ? 0x80 : 0));
    }

    // reduce per-object best prior across block (larger value, then smaller idx)
#pragma unroll
    for (int o = 0; o < NO; o++) {
        float n = bio[o], d = bdo[o]; int i = bpo[o];
        for (int off = 32; off; off >>= 1) {
            float n2 = __shfl_down(n, off, 64);
            float d2 = __shfl_down(d, off, 64);
            int   i2 = __shfl_down(i, off, 64);
            float a = n2 * d, c = n * d2;
            if (a > c || (a == c && i2 < i)) { n = n2; d = d2; i = i2; }
        }
        if (lane == 0) {
            s_redn[o * NWAVE + wv] = n;
            s_redd[o * NWAVE + wv] = d;
            s_redi[o * NWAVE + wv] = i;
        }
    }
    __syncthreads();
    if (tid < NO) {
        float n = s_redn[tid * NWAVE], d = s_redd[tid * NWAVE];
        int i = s_redi[tid * NWAVE];
#pragma unroll
        for (int w = 1; w < NWAVE; w++) {
            float n2 = s_redn[tid * NWAVE + w], d2 = s_redd[tid * NWAVE + w];
            int i2 = s_redi[tid * NWAVE + w];
            float a = n2 * d, c = n * d2;
            if (a > c || (a == c && i2 < i)) { n = n2; d = d2; i = i2; }
        }
        s_bestp[tid] = i;
    }
    __syncthreads();
    // forced assignment (serial ascending: last o wins on duplicate priors)
    if (tid == 0) {
#pragma unroll
        for (int o = 0; o < NO; o++) s_obj[s_bestp[o]] = (unsigned char)(0x80 | o);
    }
    __syncthreads();

    // ---- phase C: CE for all priors, loc L1 for positives ----
    float loc_sum = 0.0f, conf_pos = 0.0f; int np = 0;
    const float2* sc2 = (const float2*)(pscores + (size_t)b * NP * 2);
    const float4* pl4 = (const float4*)(plocs  + (size_t)b * NP * 4);
    for (int p = tid; p < NP; p += BLK) {
        unsigned m = s_obj[p];
        bool pos = (m & 0x80) != 0;
        float2 s = sc2[p];
        float mx = fmaxf(s.x, s.y);
        float dd = fabsf(s.x - s.y);
        float lse = mx + __logf(1.0f + __expf(-dd));
        float ce = lse - (pos ? s.y : s.x);
        if (pos) {
            np++;
            conf_pos += ce;
            int o = m & 15;
            float4 pr = ((const float4*)priors)[p];
            float gx = (s_bcw[o][0] - pr.x) / (pr.z / 10.0f);
            float gy = (s_bcw[o][1] - pr.y) / (pr.w / 10.0f);
            float gw = __logf(s_bcw[o][2] / pr.z) * 5.0f;
            float gh = __logf(s_bcw[o][3] / pr.w) * 5.0f;
            float4 pl = pl4[p];
            loc_sum += fabsf(pl.x - gx) + fabsf(pl.y - gy)
                     + fabsf(pl.z - gw) + fabsf(pl.w - gh);
            s_ce[p] = 0.0f;
        } else {
            s_ce[p] = ce;
        }
    }

    // n_pos reduction (need K before select)
    int npw = np;
    for (int off = 32; off; off >>= 1) npw += __shfl_down(npw, off, 64);
    if (lane == 0) s_ired[wv] = npw;
    __syncthreads();
    int n_pos = 0;
#pragma unroll
    for (int w = 0; w < NWAVE; w++) n_pos += s_ired[w];

    // ---- phase D: radix-select K-th largest of s_ce (values >= 0) ----
    // float4 LDS scans; per-pass state (prefix,k,count) is wave-uniform in
    // registers; digit selection done redundantly by every thread (no tid==0
    // serial bubble, one fewer barrier per pass); ballot-aggregated histogram
    // (plain atomicAdd version cost 4.2M LDS-conflict cycles).
    const int K = 3 * n_pos;
    const bool selAll = (K >= NP);
    float t = 0.0f;
    const float4* ce4 = (const float4*)s_ce;
    if (!selAll) {
        unsigned prefix = 0u, kk = (unsigned)K;
        bool done = false;
        for (int shift = 28; shift >= 0 && !done; shift -= 4) {
            __syncthreads();
            if (tid < 16) s_hist[tid] = 0u;
            __syncthreads();
            unsigned maskhi = (shift == 28) ? 0u : (0xFFFFFFFFu << (shift + 4));
            for (int q = tid; q < NQ; q += BLK) {
                float4 v = ce4[q];
#pragma unroll
                for (int j = 0; j < 4; j++) {
                    unsigned u = __float_as_uint(j == 0 ? v.x : j == 1 ? v.y : j == 2 ? v.z : v.w);
                    unsigned d = ((u & maskhi) == prefix) ? ((u >> shift) & 15u) : 31u;
                    unsigned long long mm = __ballot(1);   // active lanes
#pragma unroll
                    for (int bit = 0; bit < 5; bit++) {
                        unsigned long long bl = __ballot((d >> bit) & 1u);
                        mm &= ((d >> bit) & 1u) ? bl : ~bl;
                    }
                    int leader = __ffsll(mm) - 1;
                    if (lane == leader && d < 16u)
                        atomicAdd(&s_hist[d], (unsigned)__popcll(mm));
                }
            }
            __syncthreads();
            // redundant (wave-uniform) digit selection by every thread
            int dsel = 15; unsigned cnt;
            for (;; dsel--) {
                cnt = s_hist[dsel];
                if (kk <= cnt || dsel == 0) break;
                kk -= cnt;
            }
            prefix |= ((unsigned)dsel << shift);
            if (shift > 0 && cnt == 1u) {
                // unique survivor: fetch it, done
                unsigned mh = 0xFFFFFFFFu << shift;
                for (int q = tid; q < NQ; q += BLK) {
                    float4 v = ce4[q];
#pragma unroll
                    for (int j = 0; j < 4; j++) {
                        float f = (j == 0 ? v.x : j == 1 ? v.y : j == 2 ? v.z : v.w);
                        if ((__float_as_uint(f) & mh) == prefix) s_tval = f;
                    }
                }
                __syncthreads();
                t = s_tval;
                done = true;
            } else if (shift == 0) {
                t = __uint_as_float(prefix);
            }
        }
    }

    // sum of top-K = sum(v > t) + (K - cnt_gt) * t   (exact under ties)
    float sgt = 0.0f; int cgt = 0;
    for (int q = tid; q < NQ; q += BLK) {
        float4 v = ce4[q];
        if (selAll || v.x > t) { sgt += v.x; cgt++; }
        if (selAll || v.y > t) { sgt += v.y; cgt++; }
        if (selAll || v.z > t) { sgt += v.z; cgt++; }
        if (selAll || v.w > t) { sgt += v.w; cgt++; }
    }

    // ---- final block reduction of (sgt, conf_pos, loc_sum, cgt) ----
    float a = sgt, c = conf_pos, l = loc_sum; int g = cgt;
    for (int off = 32; off; off >>= 1) {
        a += __shfl_down(a, off, 64);
        c += __shfl_down(c, off, 64);
        l += __shfl_down(l, off, 64);
        g += __shfl_down(g, off, 64);
    }
    __syncthreads();
    if (lane == 0) {
        s_fred[wv] = a; s_fred[NWAVE + wv] = c; s_fred[2 * NWAVE + wv] = l;
        s_ired[wv] = g;
    }
    __syncthreads();
    if (tid == 0) {
        float sa = 0.0f, sc = 0.0f, sl = 0.0f; int sg = 0;
#pragma unroll
        for (int w = 0; w < NWAVE; w++) {
            sa += s_fred[w]; sc += s_fred[NWAVE + w]; sl += s_fred[2 * NWAVE + w];
            sg += s_ired[w];
        }
        float conf_hn = selAll ? sa : (sa + (float)(K - sg) * t);
        conf_out[b] = sc + conf_hn;
        loc_out[b]  = sl;
        npos_out[b] = n_pos;
    }
}

__global__ __launch_bounds__(256) void mbox_finalize_kernel(
    const float* __restrict__ loc_in,
    const float* __restrict__ conf_in,
    const int*   __restrict__ npos_in,
    int B, float* __restrict__ out)
{
    __shared__ float sl[4], sc[4];
    __shared__ int   si[4];
    int tid = threadIdx.x, lane = tid & 63, wv = tid >> 6;
    float l = 0.0f, c = 0.0f; int n = 0;
    for (int i = tid; i < B; i += 256) { l += loc_in[i]; c += conf_in[i]; n += npos_in[i]; }
    for (int off = 32; off; off >>= 1) {
        l += __shfl_down(l, off, 64);
        c += __shfl_down(c, off, 64);
        n += __shfl_down(n, off, 64);
    }
    if (lane == 0) { sl[wv] = l; sc[wv] = c; si[wv] = n; }
    __syncthreads();
    if (tid == 0) {
        float tl = sl[0] + sl[1] + sl[2] + sl[3];
        float tc = sc[0] + sc[1] + sc[2] + sc[3];
        int   tn = si[0] + si[1] + si[2] + si[3];
        float fn = (float)tn;
        out[0] = tc / fn + tl / (fn * 4.0f);
    }
}

extern "C" void kernel_launch(void* const* d_in, const int* in_sizes, int n_in,
                              void* d_out, int out_size, void* d_ws, size_t ws_size,
                              hipStream_t stream) {
    const float* plocs   = (const float*)d_in[0];
    const float* pscores = (const float*)d_in[1];
    const float* boxes   = (const float*)d_in[2];
    const float* priors  = (const float*)d_in[3];
    const int B = in_sizes[0] / (NP * 4);

    float* loc_ws  = (float*)d_ws;
    float* conf_ws = loc_ws + B;
    int*   np_ws   = (int*)(conf_ws + B);

    mbox_row_kernel<<<B, BLK, 0, stream>>>(plocs, pscores, boxes, priors,
                                           loc_ws, conf_ws, np_ws);
    mbox_finalize_kernel<<<1, 256, 0, stream>>>(loc_ws, conf_ws, np_ws, B, (float*)d_out);
}

// Round 5
// 214.236 us; speedup vs baseline: 1.9145x; 1.1357x over previous
//
#include <hip/hip_runtime.h>

#define NP 8732
#define NQ (NP / 4)          // 2183 float4 chunks
#define NO 16
#define BLK 256
#define NWAVE (BLK / 64)

// One block per batch row. Evidence log:
//  - BLK=512 regressed (177us vs 136us): extra waves idle at per-block barriers.
//  - __launch_bounds__ min-waves ",4" clamped VGPRs to 64 -> scratch spill
//    (52MB writes, 2.3x slower). Keep ",2".
//  - Full 16-object register cache (80+48 regs) exceeded the compiler's VGPR
//    budget (VGPR_Count stayed 104) -> arrays parked in AGPRs, v_accvgpr_read
//    per access, 167us. Fix here: pair-split objects (8/thread) so the cache
//    fits in VGPRs for real.
//  - Ballot-aggregated histograms cost more VALU than the 4.2M conflict
//    cycles they saved -> plain LDS atomicAdd.
__global__ __launch_bounds__(BLK, 2) void mbox_row_kernel(
    const float* __restrict__ plocs,    // [B,P,4]
    const float* __restrict__ pscores,  // [B,P,2]
    const float* __restrict__ boxes,    // [B,O,4] cxcy
    const float* __restrict__ priors,   // [P,4]  cxcy
    float* __restrict__ loc_out,        // [B]
    float* __restrict__ conf_out,       // [B]
    int*   __restrict__ npos_out)       // [B]
{
    const int b    = blockIdx.x;
    const int tid  = threadIdx.x;
    const int lane = tid & 63;
    const int wv   = tid >> 6;
    const int par  = tid & 1;            // 0: objects 0-7, 1: objects 8-15
    const int objLo = par << 3;

    __shared__ __align__(16) float s_ce[NP];  // ce_neg values (phase C/D)
    __shared__ unsigned char s_obj[NP];       // bit7 = pos, bits3:0 = obj
    __shared__ float s_bcw[NO][4];            // boxes cxcy
    __shared__ float s_bxy[NO][4];            // boxes corners
    __shared__ float s_barea[NO];
    __shared__ float s_redv[NO * NWAVE];      // per-object argmax: iou
    __shared__ int   s_redi[NO * NWAVE];      //                    prior idx
    __shared__ int   s_bestp[NO];
    __shared__ unsigned int s_hist[16];
    __shared__ float s_tval;
    __shared__ float s_fred[3 * NWAVE];
    __shared__ int   s_ired[NWAVE];

    // ---- load boxes, precompute corners & areas ----
    if (tid < NO * 4) ((float*)s_bcw)[tid] = boxes[(size_t)b * NO * 4 + tid];
    __syncthreads();
    if (tid < NO) {
        float cx = s_bcw[tid][0], cy = s_bcw[tid][1];
        float w  = s_bcw[tid][2], h  = s_bcw[tid][3];
        s_bxy[tid][0] = cx - w * 0.5f; s_bxy[tid][1] = cy - h * 0.5f;
        s_bxy[tid][2] = cx + w * 0.5f; s_bxy[tid][3] = cy + h * 0.5f;
        s_barea[tid] = w * h;
    }
    __syncthreads();

    // ---- register-cache THIS thread's 8 objects (40 VGPRs — fits) ----
    float rx0[8], ry0[8], rx1[8], ry1[8], ra[8];
#pragma unroll
    for (int j = 0; j < 8; j++) {
        rx0[j] = s_bxy[objLo + j][0]; ry0[j] = s_bxy[objLo + j][1];
        rx1[j] = s_bxy[objLo + j][2]; ry1[j] = s_bxy[objLo + j][3];
        ra[j]  = s_barea[objLo + j];
    }

    // ---- phase A: IoU matching; lane pair (2k,2k+1) handles prior k+128*i ----
    float tbv[8]; int tbp[8];              // per-object best over this thread's priors
#pragma unroll
    for (int j = 0; j < 8; j++) { tbv[j] = -1.0f; tbp[j] = 0; }

    for (int p = (tid >> 1); p < NP; p += (BLK / 2)) {
        float4 pr = ((const float4*)priors)[p];
        float px0 = pr.x - pr.z * 0.5f, py0 = pr.y - pr.w * 0.5f;
        float px1 = pr.x + pr.z * 0.5f, py1 = pr.y + pr.w * 0.5f;
        float areab = pr.z * pr.w;
        float bv = -1.0f; int bo = objLo;  // best over this thread's 8 objects
#pragma unroll
        for (int j = 0; j < 8; j++) {
            float ix0 = fmaxf(rx0[j], px0);
            float iy0 = fmaxf(ry0[j], py0);
            float ix1 = fminf(rx1[j], px1);
            float iy1 = fminf(ry1[j], py1);
            float iw = fmaxf(ix1 - ix0, 0.0f);
            float ih = fmaxf(iy1 - iy0, 0.0f);
            float inter = iw * ih;
            float den = ra[j] + areab - inter;
            float iou = inter * __builtin_amdgcn_rcpf(den);
            if (iou > bv)     { bv = iou; bo = objLo + j; }   // first-wins over o
            if (iou > tbv[j]) { tbv[j] = iou; tbp[j] = p; }   // first-wins over p
        }
        // combine across the lane pair (even lane covers lower object indices,
        // so on ties the even side must win)
        float vN = __shfl_xor(bv, 1, 64);
        int   oN = __shfl_xor(bo, 1, 64);
        bool take = par ? (vN >= bv) : (vN > bv);
        if (take) { bv = vN; bo = oN; }
        if (par == 0) {
            bool pos = (bv >= 0.5f);
            s_obj[p] = (unsigned char)(bo | (pos ? 0x80 : 0));
        }
    }

    // per-object reduction with even strides only (parities track disjoint
    // object sets; stride 1 would mix object j with object j+8)
#pragma unroll
    for (int j = 0; j < 8; j++) {
        float v = tbv[j]; int i = tbp[j];
        for (int off = 32; off >= 2; off >>= 1) {
            float v2 = __shfl_down(v, off, 64);
            int   i2 = __shfl_down(i, off, 64);
            if (v2 > v || (v2 == v && i2 < i)) { v = v2; i = i2; }
        }
        if (lane < 2) {   // lane0: objects 0-7, lane1: objects 8-15
            s_redv[(objLo + j) * NWAVE + wv] = v;
            s_redi[(objLo + j) * NWAVE + wv] = i;
        }
    }
    __syncthreads();
    if (tid < NO) {
        float v = s_redv[tid * NWAVE]; int i = s_redi[tid * NWAVE];
#pragma unroll
        for (int w = 1; w < NWAVE; w++) {
            float v2 = s_redv[tid * NWAVE + w]; int i2 = s_redi[tid * NWAVE + w];
            if (v2 > v || (v2 == v && i2 < i)) { v = v2; i = i2; }
        }
        s_bestp[tid] = i;
    }
    __syncthreads();
    // forced assignment (serial ascending: last o wins on duplicate priors)
    if (tid == 0) {
#pragma unroll
        for (int o = 0; o < NO; o++) s_obj[s_bestp[o]] = (unsigned char)(0x80 | o);
    }
    __syncthreads();

    // ---- phase C: CE for all priors, loc L1 for positives ----
    float loc_sum = 0.0f, conf_pos = 0.0f; int np = 0;
    const float2* sc2 = (const float2*)(pscores + (size_t)b * NP * 2);
    const float4* pl4 = (const float4*)(plocs  + (size_t)b * NP * 4);
    for (int p = tid; p < NP; p += BLK) {
        unsigned m = s_obj[p];
        bool pos = (m & 0x80) != 0;
        float2 s = sc2[p];
        float mx = fmaxf(s.x, s.y);
        float dd = fabsf(s.x - s.y);
        float lse = mx + __logf(1.0f + __expf(-dd));
        float ce = lse - (pos ? s.y : s.x);
        if (pos) {
            np++;
            conf_pos += ce;
            int o = m & 15;
            float4 pr = ((const float4*)priors)[p];
            float gx = (s_bcw[o][0] - pr.x) / (pr.z / 10.0f);
            float gy = (s_bcw[o][1] - pr.y) / (pr.w / 10.0f);
            float gw = __logf(s_bcw[o][2] / pr.z) * 5.0f;
            float gh = __logf(s_bcw[o][3] / pr.w) * 5.0f;
            float4 pl = pl4[p];
            loc_sum += fabsf(pl.x - gx) + fabsf(pl.y - gy)
                     + fabsf(pl.z - gw) + fabsf(pl.w - gh);
            s_ce[p] = 0.0f;
        } else {
            s_ce[p] = ce;
        }
    }

    // n_pos reduction (need K before select)
    int npw = np;
    for (int off = 32; off; off >>= 1) npw += __shfl_down(npw, off, 64);
    if (lane == 0) s_ired[wv] = npw;
    __syncthreads();
    int n_pos = 0;
#pragma unroll
    for (int w = 0; w < NWAVE; w++) n_pos += s_ired[w];

    // ---- phase D: radix-select K-th largest of s_ce (values >= 0) ----
    // float4 scans, plain LDS atomic histogram, redundant wave-uniform digit
    // selection (no tid==0 bubble), early exit when the bucket is unique.
    const int K = 3 * n_pos;
    const bool selAll = (K >= NP);
    float t = 0.0f;
    const float4* ce4 = (const float4*)s_ce;
    if (!selAll) {
        unsigned prefix = 0u, kk = (unsigned)K;
        bool done = false;
        for (int shift = 28; shift >= 0 && !done; shift -= 4) {
            __syncthreads();
            if (tid < 16) s_hist[tid] = 0u;
            __syncthreads();
            unsigned maskhi = (shift == 28) ? 0u : (0xFFFFFFFFu << (shift + 4));
            for (int q = tid; q < NQ; q += BLK) {
                float4 v = ce4[q];
#pragma unroll
                for (int j = 0; j < 4; j++) {
                    unsigned u = __float_as_uint(j == 0 ? v.x : j == 1 ? v.y : j == 2 ? v.z : v.w);
                    if ((u & maskhi) == prefix)
                        atomicAdd(&s_hist[(u >> shift) & 15u], 1u);
                }
            }
            __syncthreads();
            int dsel = 15; unsigned cnt;
            for (;; dsel--) {
                cnt = s_hist[dsel];
                if (kk <= cnt || dsel == 0) break;
                kk -= cnt;
            }
            prefix |= ((unsigned)dsel << shift);
            if (shift > 0 && cnt == 1u) {
                unsigned mh = 0xFFFFFFFFu << shift;
                for (int q = tid; q < NQ; q += BLK) {
                    float4 v = ce4[q];
#pragma unroll
                    for (int j = 0; j < 4; j++) {
                        float f = (j == 0 ? v.x : j == 1 ? v.y : j == 2 ? v.z : v.w);
                        if ((__float_as_uint(f) & mh) == prefix) s_tval = f;
                    }
                }
                __syncthreads();
                t = s_tval;
                done = true;
            } else if (shift == 0) {
                t = __uint_as_float(prefix);
            }
        }
    }

    // sum of top-K = sum(v > t) + (K - cnt_gt) * t   (exact under ties)
    float sgt = 0.0f; int cgt = 0;
    for (int q = tid; q < NQ; q += BLK) {
        float4 v = ce4[q];
        if (selAll || v.x > t) { sgt += v.x; cgt++; }
        if (selAll || v.y > t) { sgt += v.y; cgt++; }
        if (selAll || v.z > t) { sgt += v.z; cgt++; }
        if (selAll || v.w > t) { sgt += v.w; cgt++; }
    }

    // ---- final block reduction of (sgt, conf_pos, loc_sum, cgt) ----
    float a = sgt, c = conf_pos, l = loc_sum; int g = cgt;
    for (int off = 32; off; off >>= 1) {
        a += __shfl_down(a, off, 64);
        c += __shfl_down(c, off, 64);
        l += __shfl_down(l, off, 64);
        g += __shfl_down(g, off, 64);
    }
    __syncthreads();
    if (lane == 0) {
        s_fred[wv] = a; s_fred[NWAVE + wv] = c; s_fred[2 * NWAVE + wv] = l;
        s_ired[wv] = g;
    }
    __syncthreads();
    if (tid == 0) {
        float sa = 0.0f, sc = 0.0f, sl = 0.0f; int sg = 0;
#pragma unroll
        for (int w = 0; w < NWAVE; w++) {
            sa += s_fred[w]; sc += s_fred[NWAVE + w]; sl += s_fred[2 * NWAVE + w];
            sg += s_ired[w];
        }
        float conf_hn = selAll ? sa : (sa + (float)(K - sg) * t);
        conf_out[b] = sc + conf_hn;
        loc_out[b]  = sl;
        npos_out[b] = n_pos;
    }
}

__global__ __launch_bounds__(256) void mbox_finalize_kernel(
    const float* __restrict__ loc_in,
    const float* __restrict__ conf_in,
    const int*   __restrict__ npos_in,
    int B, float* __restrict__ out)
{
    __shared__ float sl[4], sc[4];
    __shared__ int   si[4];
    int tid = threadIdx.x, lane = tid & 63, wv = tid >> 6;
    float l = 0.0f, c = 0.0f; int n = 0;
    for (int i = tid; i < B; i += 256) { l += loc_in[i]; c += conf_in[i]; n += npos_in[i]; }
    for (int off = 32; off; off >>= 1) {
        l += __shfl_down(l, off, 64);
        c += __shfl_down(c, off, 64);
        n += __shfl_down(n, off, 64);
    }
    if (lane == 0) { sl[wv] = l; sc[wv] = c; si[wv] = n; }
    __syncthreads();
    if (tid == 0) {
        float tl = sl[0] + sl[1] + sl[2] + sl[3];
        float tc = sc[0] + sc[1] + sc[2] + sc[3];
        int   tn = si[0] + si[1] + si[2] + si[3];
        float fn = (float)tn;
        out[0] = tc / fn + tl / (fn * 4.0f);
    }
}

extern "C" void kernel_launch(void* const* d_in, const int* in_sizes, int n_in,
                              void* d_out, int out_size, void* d_ws, size_t ws_size,
                              hipStream_t stream) {
    const float* plocs   = (const float*)d_in[0];
    const float* pscores = (const float*)d_in[1];
    const float* boxes   = (const float*)d_in[2];
    const float* priors  = (const float*)d_in[3];
    const int B = in_sizes[0] / (NP * 4);

    float* loc_ws  = (float*)d_ws;
    float* conf_ws = loc_ws + B;
    int*   np_ws   = (int*)(conf_ws + B);

    mbox_row_kernel<<<B, BLK, 0, stream>>>(plocs, pscores, boxes, priors,
                                           loc_ws, conf_ws, np_ws);
    mbox_finalize_kernel<<<1, 256, 0, stream>>>(loc_ws, conf_ws, np_ws, B, (float*)d_out);
}

// Round 6
// 201.049 us; speedup vs baseline: 2.0401x; 1.0656x over previous
//
#include <hip/hip_runtime.h>

#define NP 8732
#define NQ (NP / 4)          // 2183 float4 chunks
#define NO 16
#define BLK 256
#define NWAVE (BLK / 64)
#define SPLIT 4
#define CHUNK (NP / SPLIT)   // 2183 exactly

// ---------------------------------------------------------------------------
// Evidence log:
//  - One block/row is grid-limited to 2 blocks/CU (21% occupancy); all phases
//    stall on latency (VALUBusy 41-53%, time 3-4x the VALU floor).
//  - BLK=512 regressed (barrier pile-up); launch_bounds ",4" spilled (52MB).
//  - 16-object reg cache overflowed to AGPRs (VGPR stuck 104, v_accvgpr per
//    access); pair-split 8-object cache fits (VGPR 68) and won.
//  - 8-pass radix select: 24 barriers + 8 full scans; replaced here by
//    3-level 4096-bin histogram select (3 scans, exact from counts).
// Round 6: match phase split to its own kernel at grid B*SPLIT (8 blocks/CU).
// ---------------------------------------------------------------------------

// Kernel A: match a CHUNK of priors vs all 16 objects. Writes per-prior obj
// byte (bit7=pos, bits3:0=obj) and per-(row,object,split) best candidate.
__global__ __launch_bounds__(BLK, 2) void match_kernel(
    const float* __restrict__ boxes,    // [B,O,4] cxcy
    const float* __restrict__ priors,   // [P,4]  cxcy
    unsigned char* __restrict__ g_obj,  // [B,NP]
    float* __restrict__ g_bv,           // [B,16,SPLIT]
    int*   __restrict__ g_bi)           // [B,16,SPLIT]
{
    const int b    = blockIdx.x;
    const int s    = blockIdx.y;
    const int tid  = threadIdx.x;
    const int lane = tid & 63;
    const int wv   = tid >> 6;
    const int par  = tid & 1;            // 0: objects 0-7, 1: objects 8-15
    const int objLo = par << 3;
    const int lo = s * CHUNK, hi = lo + CHUNK;

    __shared__ float s_bxy[NO][4];
    __shared__ float s_barea[NO];
    __shared__ float s_redv[NO * NWAVE];
    __shared__ int   s_redi[NO * NWAVE];

    if (tid < NO) {
        const float* bx = boxes + (size_t)b * NO * 4 + tid * 4;
        float cx = bx[0], cy = bx[1], w = bx[2], h = bx[3];
        s_bxy[tid][0] = cx - w * 0.5f; s_bxy[tid][1] = cy - h * 0.5f;
        s_bxy[tid][2] = cx + w * 0.5f; s_bxy[tid][3] = cy + h * 0.5f;
        s_barea[tid] = w * h;
    }
    __syncthreads();

    // register-cache this thread's 8 objects (fits in VGPRs: VGPR_Count 68)
    float rx0[8], ry0[8], rx1[8], ry1[8], ra[8];
#pragma unroll
    for (int j = 0; j < 8; j++) {
        rx0[j] = s_bxy[objLo + j][0]; ry0[j] = s_bxy[objLo + j][1];
        rx1[j] = s_bxy[objLo + j][2]; ry1[j] = s_bxy[objLo + j][3];
        ra[j]  = s_barea[objLo + j];
    }

    float tbv[8]; int tbp[8];
#pragma unroll
    for (int j = 0; j < 8; j++) { tbv[j] = -1.0f; tbp[j] = lo; }

    unsigned char* obj_row = g_obj + (size_t)b * NP;
    for (int p = lo + (tid >> 1); p < hi; p += (BLK / 2)) {
        float4 pr = ((const float4*)priors)[p];
        float px0 = pr.x - pr.z * 0.5f, py0 = pr.y - pr.w * 0.5f;
        float px1 = pr.x + pr.z * 0.5f, py1 = pr.y + pr.w * 0.5f;
        float areab = pr.z * pr.w;
        float bv = -1.0f; int bo = objLo;
#pragma unroll
        for (int j = 0; j < 8; j++) {
            float ix0 = fmaxf(rx0[j], px0);
            float iy0 = fmaxf(ry0[j], py0);
            float ix1 = fminf(rx1[j], px1);
            float iy1 = fminf(ry1[j], py1);
            float iw = fmaxf(ix1 - ix0, 0.0f);
            float ih = fmaxf(iy1 - iy0, 0.0f);
            float inter = iw * ih;
            float den = ra[j] + areab - inter;
            float iou = inter * __builtin_amdgcn_rcpf(den);
            if (iou > bv)     { bv = iou; bo = objLo + j; }   // first-wins over o
            if (iou > tbv[j]) { tbv[j] = iou; tbp[j] = p; }   // first-wins over p
        }
        // combine lane pair (even lane = lower object indices wins ties)
        float vN = __shfl_xor(bv, 1, 64);
        int   oN = __shfl_xor(bo, 1, 64);
        bool take = par ? (vN >= bv) : (vN > bv);
        if (take) { bv = vN; bo = oN; }
        if (par == 0) {
            bool pos = (bv >= 0.5f);
            obj_row[p] = (unsigned char)(bo | (pos ? 0x80 : 0));
        }
    }

    // per-object block reduction (even strides keep parities' object sets apart)
#pragma unroll
    for (int j = 0; j < 8; j++) {
        float v = tbv[j]; int i = tbp[j];
        for (int off = 32; off >= 2; off >>= 1) {
            float v2 = __shfl_down(v, off, 64);
            int   i2 = __shfl_down(i, off, 64);
            if (v2 > v || (v2 == v && i2 < i)) { v = v2; i = i2; }
        }
        if (lane < 2) {
            s_redv[(objLo + j) * NWAVE + wv] = v;
            s_redi[(objLo + j) * NWAVE + wv] = i;
        }
    }
    __syncthreads();
    if (tid < NO) {
        float v = s_redv[tid * NWAVE]; int i = s_redi[tid * NWAVE];
#pragma unroll
        for (int w = 1; w < NWAVE; w++) {
            float v2 = s_redv[tid * NWAVE + w]; int i2 = s_redi[tid * NWAVE + w];
            if (v2 > v || (v2 == v && i2 < i)) { v = v2; i = i2; }
        }
        g_bv[((size_t)b * NO + tid) * SPLIT + s] = v;
        g_bi[((size_t)b * NO + tid) * SPLIT + s] = i;
    }
}

// Histogram bin selection: given filled hist (4096 bins), find bin holding the
// kk-th largest (counting from the top); returns bin, updates kk to the rank
// within the bin. Uses s_part/s_csuf[256], s_sel[2]. All-uniform result.
__device__ __forceinline__ int hist_select(unsigned* hist, unsigned* s_part,
                                           unsigned* s_csuf, unsigned* s_sel,
                                           unsigned& kk, int tid, int lane, int wv)
{
    unsigned ps = 0;
#pragma unroll
    for (int i = 0; i < 16; i++) ps += hist[tid * 16 + i];
    s_part[tid] = ps;
    __syncthreads();
    if (wv == 0) {
        unsigned c0 = s_part[4 * lane + 0], c1 = s_part[4 * lane + 1];
        unsigned c2 = s_part[4 * lane + 2], c3 = s_part[4 * lane + 3];
        unsigned g = c0 + c1 + c2 + c3;
        unsigned incl = g;
#pragma unroll
        for (int off = 1; off < 64; off <<= 1) {
            unsigned o = __shfl_down(incl, off, 64);
            if (lane + off < 64) incl += o;
        }
        unsigned excl = incl - g;           // count in chunks > 4*lane+3
        s_csuf[4 * lane + 3] = excl;
        s_csuf[4 * lane + 2] = excl + c3;
        s_csuf[4 * lane + 1] = excl + c3 + c2;
        s_csuf[4 * lane + 0] = excl + c3 + c2 + c1;
    }
    __syncthreads();
    unsigned base = s_csuf[tid];            // count in bins >= 16*(tid+1)
    if (base < kk && kk <= base + s_part[tid]) {   // exactly one thread
        unsigned run = base;
        for (int i = 15; i >= 0; i--) {
            unsigned h = hist[tid * 16 + i];
            if (kk <= run + h) { s_sel[0] = (unsigned)(tid * 16 + i); s_sel[1] = kk - run; break; }
            run += h;
        }
    }
    __syncthreads();
    kk = s_sel[1];
    return (int)s_sel[0];
}

// Kernel B: per-row losses. Reads obj table + best candidates; forced
// assignment; CE + loc-L1; 3-level histogram select for hard negatives.
__global__ __launch_bounds__(BLK, 2) void loss_kernel(
    const float* __restrict__ plocs,    // [B,P,4]
    const float* __restrict__ pscores,  // [B,P,2]
    const float* __restrict__ boxes,    // [B,O,4]
    const float* __restrict__ priors,   // [P,4]
    const unsigned char* __restrict__ g_obj,
    const float* __restrict__ g_bv,
    const int*   __restrict__ g_bi,
    float* __restrict__ loc_out,
    float* __restrict__ conf_out,
    int*   __restrict__ npos_out)
{
    const int b    = blockIdx.x;
    const int tid  = threadIdx.x;
    const int lane = tid & 63;
    const int wv   = tid >> 6;

    __shared__ __align__(16) float s_ce[NP];
    __shared__ unsigned char s_obj[NP];
    __shared__ unsigned s_hist[4096];
    __shared__ unsigned s_part[256];
    __shared__ unsigned s_csuf[256];
    __shared__ unsigned s_sel[2];
    __shared__ float s_bcw[NO][4];
    __shared__ int   s_bestp[NO];
    __shared__ float s_fred[3 * NWAVE];
    __shared__ int   s_ired[NWAVE];

    // load obj bytes + boxes; reduce forced-assignment candidates
    const unsigned char* obj_row = g_obj + (size_t)b * NP;
    for (int p = tid; p < NP; p += BLK) s_obj[p] = obj_row[p];
    if (tid < NO * 4) ((float*)s_bcw)[tid] = boxes[(size_t)b * NO * 4 + tid];
    if (tid < NO) {
        // splits cover ascending p ranges; ascending-s strict-> keeps first idx
        const float* bv = g_bv + ((size_t)b * NO + tid) * SPLIT;
        const int*   bi = g_bi + ((size_t)b * NO + tid) * SPLIT;
        float v = bv[0]; int i = bi[0];
#pragma unroll
        for (int s = 1; s < SPLIT; s++) {
            float v2 = bv[s]; int i2 = bi[s];
            if (v2 > v || (v2 == v && i2 < i)) { v = v2; i = i2; }
        }
        s_bestp[tid] = i;
    }
    __syncthreads();
    if (tid == 0) {   // serial ascending: last o wins on duplicate priors
#pragma unroll
        for (int o = 0; o < NO; o++) s_obj[s_bestp[o]] = (unsigned char)(0x80 | o);
    }
    __syncthreads();

    // phase C: CE for all priors, loc L1 for positives
    float loc_sum = 0.0f, conf_pos = 0.0f; int np = 0;
    const float2* sc2 = (const float2*)(pscores + (size_t)b * NP * 2);
    const float4* pl4 = (const float4*)(plocs  + (size_t)b * NP * 4);
    for (int p = tid; p < NP; p += BLK) {
        unsigned m = s_obj[p];
        bool pos = (m & 0x80) != 0;
        float2 s = sc2[p];
        float mx = fmaxf(s.x, s.y);
        float dd = fabsf(s.x - s.y);
        float lse = mx + __logf(1.0f + __expf(-dd));
        float ce = lse - (pos ? s.y : s.x);
        if (pos) {
            np++;
            conf_pos += ce;
            int o = m & 15;
            float4 pr = ((const float4*)priors)[p];
            float gx = (s_bcw[o][0] - pr.x) / (pr.z / 10.0f);
            float gy = (s_bcw[o][1] - pr.y) / (pr.w / 10.0f);
            float gw = __logf(s_bcw[o][2] / pr.z) * 5.0f;
            float gh = __logf(s_bcw[o][3] / pr.w) * 5.0f;
            float4 pl = pl4[p];
            loc_sum += fabsf(pl.x - gx) + fabsf(pl.y - gy)
                     + fabsf(pl.z - gw) + fabsf(pl.w - gh);
            s_ce[p] = 0.0f;
        } else {
            s_ce[p] = ce;
        }
    }

    int npw = np;
    for (int off = 32; off; off >>= 1) npw += __shfl_down(npw, off, 64);
    if (lane == 0) s_ired[wv] = npw;
    __syncthreads();
    int n_pos = 0;
#pragma unroll
    for (int w = 0; w < NWAVE; w++) n_pos += s_ired[w];

    // phase D: 3-level histogram select of the K-th largest CE value.
    // Keys: bits[30:19] (<=4080 for any non-negative float), [18:7], [6:0].
    const int K = 3 * n_pos;
    const bool selAll = (K >= NP);
    float t = 0.0f;
    const float4* ce4 = (const float4*)s_ce;
    if (!selAll) {
        unsigned kk = (unsigned)K;
        // level 1
        for (int i = tid; i < 4096; i += BLK) s_hist[i] = 0u;
        __syncthreads();
        for (int q = tid; q < NQ; q += BLK) {
            float4 v = ce4[q];
            atomicAdd(&s_hist[__float_as_uint(v.x) >> 19], 1u);
            atomicAdd(&s_hist[__float_as_uint(v.y) >> 19], 1u);
            atomicAdd(&s_hist[__float_as_uint(v.z) >> 19], 1u);
            atomicAdd(&s_hist[__float_as_uint(v.w) >> 19], 1u);
        }
        __syncthreads();
        unsigned b1 = (unsigned)hist_select(s_hist, s_part, s_csuf, s_sel, kk, tid, lane, wv);
        // level 2
        for (int i = tid; i < 4096; i += BLK) s_hist[i] = 0u;
        __syncthreads();
        for (int q = tid; q < NQ; q += BLK) {
            float4 v = ce4[q];
#pragma unroll
            for (int j = 0; j < 4; j++) {
                unsigned u = __float_as_uint(j == 0 ? v.x : j == 1 ? v.y : j == 2 ? v.z : v.w);
                if ((u >> 19) == b1) atomicAdd(&s_hist[(u >> 7) & 0xFFFu], 1u);
            }
        }
        __syncthreads();
        unsigned b2 = (unsigned)hist_select(s_hist, s_part, s_csuf, s_sel, kk, tid, lane, wv);
        unsigned p2 = (b1 << 12) | b2;
        // level 3 (128 live bins; reuse the 4096 array)
        for (int i = tid; i < 4096; i += BLK) s_hist[i] = 0u;
        __syncthreads();
        for (int q = tid; q < NQ; q += BLK) {
            float4 v = ce4[q];
#pragma unroll
            for (int j = 0; j < 4; j++) {
                unsigned u = __float_as_uint(j == 0 ? v.x : j == 1 ? v.y : j == 2 ? v.z : v.w);
                if ((u >> 7) == p2) atomicAdd(&s_hist[u & 0x7Fu], 1u);
            }
        }
        __syncthreads();
        unsigned b3 = (unsigned)hist_select(s_hist, s_part, s_csuf, s_sel, kk, tid, lane, wv);
        t = __uint_as_float((p2 << 7) | b3);
    }

    // sum of top-K = sum(v > t) + (K - cnt_gt) * t   (exact under ties)
    float sgt = 0.0f; int cgt = 0;
    for (int q = tid; q < NQ; q += BLK) {
        float4 v = ce4[q];
        if (selAll || v.x > t) { sgt += v.x; cgt++; }
        if (selAll || v.y > t) { sgt += v.y; cgt++; }
        if (selAll || v.z > t) { sgt += v.z; cgt++; }
        if (selAll || v.w > t) { sgt += v.w; cgt++; }
    }

    float a = sgt, c = conf_pos, l = loc_sum; int g = cgt;
    for (int off = 32; off; off >>= 1) {
        a += __shfl_down(a, off, 64);
        c += __shfl_down(c, off, 64);
        l += __shfl_down(l, off, 64);
        g += __shfl_down(g, off, 64);
    }
    __syncthreads();
    if (lane == 0) {
        s_fred[wv] = a; s_fred[NWAVE + wv] = c; s_fred[2 * NWAVE + wv] = l;
        s_ired[wv] = g;
    }
    __syncthreads();
    if (tid == 0) {
        float sa = 0.0f, sc = 0.0f, sl = 0.0f; int sg = 0;
#pragma unroll
        for (int w = 0; w < NWAVE; w++) {
            sa += s_fred[w]; sc += s_fred[NWAVE + w]; sl += s_fred[2 * NWAVE + w];
            sg += s_ired[w];
        }
        float conf_hn = selAll ? sa : (sa + (float)(K - sg) * t);
        conf_out[b] = sc + conf_hn;
        loc_out[b]  = sl;
        npos_out[b] = n_pos;
    }
}

// ------------------------- round-5 monolith (fallback if ws too small) -----
__global__ __launch_bounds__(BLK, 2) void mbox_row_kernel(
    const float* __restrict__ plocs, const float* __restrict__ pscores,
    const float* __restrict__ boxes, const float* __restrict__ priors,
    float* __restrict__ loc_out, float* __restrict__ conf_out,
    int* __restrict__ npos_out)
{
    const int b = blockIdx.x, tid = threadIdx.x, lane = tid & 63, wv = tid >> 6;
    const int par = tid & 1, objLo = par << 3;
    __shared__ __align__(16) float s_ce[NP];
    __shared__ unsigned char s_obj[NP];
    __shared__ float s_bcw[NO][4], s_bxy[NO][4], s_barea[NO];
    __shared__ float s_redv[NO * NWAVE]; __shared__ int s_redi[NO * NWAVE];
    __shared__ int s_bestp[NO];
    __shared__ unsigned s_hist16[16];
    __shared__ float s_tval;
    __shared__ float s_fred[3 * NWAVE]; __shared__ int s_ired[NWAVE];

    if (tid < NO * 4) ((float*)s_bcw)[tid] = boxes[(size_t)b * NO * 4 + tid];
    __syncthreads();
    if (tid < NO) {
        float cx = s_bcw[tid][0], cy = s_bcw[tid][1], w = s_bcw[tid][2], h = s_bcw[tid][3];
        s_bxy[tid][0] = cx - w * 0.5f; s_bxy[tid][1] = cy - h * 0.5f;
        s_bxy[tid][2] = cx + w * 0.5f; s_bxy[tid][3] = cy + h * 0.5f;
        s_barea[tid] = w * h;
    }
    __syncthreads();
    float rx0[8], ry0[8], rx1[8], ry1[8], ra[8];
#pragma unroll
    for (int j = 0; j < 8; j++) {
        rx0[j] = s_bxy[objLo + j][0]; ry0[j] = s_bxy[objLo + j][1];
        rx1[j] = s_bxy[objLo + j][2]; ry1[j] = s_bxy[objLo + j][3];
        ra[j]  = s_barea[objLo + j];
    }
    float tbv[8]; int tbp[8];
#pragma unroll
    for (int j = 0; j < 8; j++) { tbv[j] = -1.0f; tbp[j] = 0; }
    for (int p = (tid >> 1); p < NP; p += (BLK / 2)) {
        float4 pr = ((const float4*)priors)[p];
        float px0 = pr.x - pr.z * 0.5f, py0 = pr.y - pr.w * 0.5f;
        float px1 = pr.x + pr.z * 0.5f, py1 = pr.y + pr.w * 0.5f;
        float areab = pr.z * pr.w;
        float bv = -1.0f; int bo = objLo;
#pragma unroll
        for (int j = 0; j < 8; j++) {
            float ix0 = fmaxf(rx0[j], px0), iy0 = fmaxf(ry0[j], py0);
            float ix1 = fminf(rx1[j], px1), iy1 = fminf(ry1[j], py1);
            float iw = fmaxf(ix1 - ix0, 0.0f), ih = fmaxf(iy1 - iy0, 0.0f);
            float inter = iw * ih, den = ra[j] + areab - inter;
            float iou = inter * __builtin_amdgcn_rcpf(den);
            if (iou > bv) { bv = iou; bo = objLo + j; }
            if (iou > tbv[j]) { tbv[j] = iou; tbp[j] = p; }
        }
        float vN = __shfl_xor(bv, 1, 64); int oN = __shfl_xor(bo, 1, 64);
        bool take = par ? (vN >= bv) : (vN > bv);
        if (take) { bv = vN; bo = oN; }
        if (par == 0) s_obj[p] = (unsigned char)(bo | ((bv >= 0.5f) ? 0x80 : 0));
    }
#pragma unroll
    for (int j = 0; j < 8; j++) {
        float v = tbv[j]; int i = tbp[j];
        for (int off = 32; off >= 2; off >>= 1) {
            float v2 = __shfl_down(v, off, 64); int i2 = __shfl_down(i, off, 64);
            if (v2 > v || (v2 == v && i2 < i)) { v = v2; i = i2; }
        }
        if (lane < 2) { s_redv[(objLo + j) * NWAVE + wv] = v; s_redi[(objLo + j) * NWAVE + wv] = i; }
    }
    __syncthreads();
    if (tid < NO) {
        float v = s_redv[tid * NWAVE]; int i = s_redi[tid * NWAVE];
#pragma unroll
        for (int w = 1; w < NWAVE; w++) {
            float v2 = s_redv[tid * NWAVE + w]; int i2 = s_redi[tid * NWAVE + w];
            if (v2 > v || (v2 == v && i2 < i)) { v = v2; i = i2; }
        }
        s_bestp[tid] = i;
    }
    __syncthreads();
    if (tid == 0) {
#pragma unroll
        for (int o = 0; o < NO; o++) s_obj[s_bestp[o]] = (unsigned char)(0x80 | o);
    }
    __syncthreads();
    float loc_sum = 0.0f, conf_pos = 0.0f; int np = 0;
    const float2* sc2 = (const float2*)(pscores + (size_t)b * NP * 2);
    const float4* pl4 = (const float4*)(plocs + (size_t)b * NP * 4);
    for (int p = tid; p < NP; p += BLK) {
        unsigned m = s_obj[p]; bool pos = (m & 0x80) != 0;
        float2 s = sc2[p];
        float mx = fmaxf(s.x, s.y), dd = fabsf(s.x - s.y);
        float ce = mx + __logf(1.0f + __expf(-dd)) - (pos ? s.y : s.x);
        if (pos) {
            np++; conf_pos += ce;
            int o = m & 15;
            float4 pr = ((const float4*)priors)[p];
            float gx = (s_bcw[o][0] - pr.x) / (pr.z / 10.0f);
            float gy = (s_bcw[o][1] - pr.y) / (pr.w / 10.0f);
            float gw = __logf(s_bcw[o][2] / pr.z) * 5.0f;
            float gh = __logf(s_bcw[o][3] / pr.w) * 5.0f;
            float4 pl = pl4[p];
            loc_sum += fabsf(pl.x - gx) + fabsf(pl.y - gy) + fabsf(pl.z - gw) + fabsf(pl.w - gh);
            s_ce[p] = 0.0f;
        } else s_ce[p] = ce;
    }
    int npw = np;
    for (int off = 32; off; off >>= 1) npw += __shfl_down(npw, off, 64);
    if (lane == 0) s_ired[wv] = npw;
    __syncthreads();
    int n_pos = 0;
#pragma unroll
    for (int w = 0; w < NWAVE; w++) n_pos += s_ired[w];
    const int K = 3 * n_pos; const bool selAll = (K >= NP);
    float t = 0.0f;
    const float4* ce4 = (const float4*)s_ce;
    if (!selAll) {
        unsigned prefix = 0u, kk = (unsigned)K; bool done = false;
        for (int shift = 28; shift >= 0 && !done; shift -= 4) {
            __syncthreads();
            if (tid < 16) s_hist16[tid] = 0u;
            __syncthreads();
            unsigned maskhi = (shift == 28) ? 0u : (0xFFFFFFFFu << (shift + 4));
            for (int q = tid; q < NQ; q += BLK) {
                float4 v = ce4[q];
#pragma unroll
                for (int j = 0; j < 4; j++) {
                    unsigned u = __float_as_uint(j == 0 ? v.x : j == 1 ? v.y : j == 2 ? v.z : v.w);
                    if ((u & maskhi) == prefix) atomicAdd(&s_hist16[(u >> shift) & 15u], 1u);
                }
            }
            __syncthreads();
            int dsel = 15; unsigned cnt;
            for (;; dsel--) { cnt = s_hist16[dsel]; if (kk <= cnt || dsel == 0) break; kk -= cnt; }
            prefix |= ((unsigned)dsel << shift);
            if (shift > 0 && cnt == 1u) {
                unsigned mh = 0xFFFFFFFFu << shift;
                for (int q = tid; q < NQ; q += BLK) {
                    float4 v = ce4[q];
#pragma unroll
                    for (int j = 0; j < 4; j++) {
                        float f = (j == 0 ? v.x : j == 1 ? v.y : j == 2 ? v.z : v.w);
                        if ((__float_as_uint(f) & mh) == prefix) s_tval = f;
                    }
                }
                __syncthreads();
                t = s_tval; done = true;
            } else if (shift == 0) t = __uint_as_float(prefix);
        }
    }
    float sgt = 0.0f; int cgt = 0;
    for (int q = tid; q < NQ; q += BLK) {
        float4 v = ce4[q];
        if (selAll || v.x > t) { sgt += v.x; cgt++; }
        if (selAll || v.y > t) { sgt += v.y; cgt++; }
        if (selAll || v.z > t) { sgt += v.z; cgt++; }
        if (selAll || v.w > t) { sgt += v.w; cgt++; }
    }
    float a = sgt, c = conf_pos, l = loc_sum; int g = cgt;
    for (int off = 32; off; off >>= 1) {
        a += __shfl_down(a, off, 64); c += __shfl_down(c, off, 64);
        l += __shfl_down(l, off, 64); g += __shfl_down(g, off, 64);
    }
    __syncthreads();
    if (lane == 0) { s_fred[wv] = a; s_fred[NWAVE + wv] = c; s_fred[2 * NWAVE + wv] = l; s_ired[wv] = g; }
    __syncthreads();
    if (tid == 0) {
        float sa = 0, sc = 0, sl = 0; int sg = 0;
#pragma unroll
        for (int w = 0; w < NWAVE; w++) { sa += s_fred[w]; sc += s_fred[NWAVE + w]; sl += s_fred[2 * NWAVE + w]; sg += s_ired[w]; }
        float conf_hn = selAll ? sa : (sa + (float)(K - sg) * t);
        conf_out[b] = sc + conf_hn; loc_out[b] = sl; npos_out[b] = n_pos;
    }
}

__global__ __launch_bounds__(256) void mbox_finalize_kernel(
    const float* __restrict__ loc_in, const float* __restrict__ conf_in,
    const int* __restrict__ npos_in, int B, float* __restrict__ out)
{
    __shared__ float sl[4], sc[4];
    __shared__ int si[4];
    int tid = threadIdx.x, lane = tid & 63, wv = tid >> 6;
    float l = 0.0f, c = 0.0f; int n = 0;
    for (int i = tid; i < B; i += 256) { l += loc_in[i]; c += conf_in[i]; n += npos_in[i]; }
    for (int off = 32; off; off >>= 1) {
        l += __shfl_down(l, off, 64);
        c += __shfl_down(c, off, 64);
        n += __shfl_down(n, off, 64);
    }
    if (lane == 0) { sl[wv] = l; sc[wv] = c; si[wv] = n; }
    __syncthreads();
    if (tid == 0) {
        float tl = sl[0] + sl[1] + sl[2] + sl[3];
        float tc = sc[0] + sc[1] + sc[2] + sc[3];
        int tn = si[0] + si[1] + si[2] + si[3];
        float fn = (float)tn;
        out[0] = tc / fn + tl / (fn * 4.0f);
    }
}

extern "C" void kernel_launch(void* const* d_in, const int* in_sizes, int n_in,
                              void* d_out, int out_size, void* d_ws, size_t ws_size,
                              hipStream_t stream) {
    const float* plocs   = (const float*)d_in[0];
    const float* pscores = (const float*)d_in[1];
    const float* boxes   = (const float*)d_in[2];
    const float* priors  = (const float*)d_in[3];
    const int B = in_sizes[0] / (NP * 4);

    float* loc_ws  = (float*)d_ws;
    float* conf_ws = loc_ws + B;
    int*   np_ws   = (int*)(conf_ws + B);
    float* g_bv    = (float*)(np_ws + B);
    int*   g_bi    = (int*)(g_bv + (size_t)B * NO * SPLIT);
    unsigned char* g_obj = (unsigned char*)(g_bi + (size_t)B * NO * SPLIT);
    size_t need = (size_t)(3 * B) * 4 + (size_t)B * NO * SPLIT * 8 + (size_t)B * NP;

    if (ws_size >= need) {
        match_kernel<<<dim3(B, SPLIT), BLK, 0, stream>>>(boxes, priors, g_obj, g_bv, g_bi);
        loss_kernel<<<B, BLK, 0, stream>>>(plocs, pscores, boxes, priors,
                                           g_obj, g_bv, g_bi, loc_ws, conf_ws, np_ws);
    } else {
        mbox_row_kernel<<<B, BLK, 0, stream>>>(plocs, pscores, boxes, priors,
                                               loc_ws, conf_ws, np_ws);
    }
    mbox_finalize_kernel<<<1, 256, 0, stream>>>(loc_ws, conf_ws, np_ws, B, (float*)d_out);
}

// Round 7
// 196.555 us; speedup vs baseline: 2.0868x; 1.0229x over previous
//
#include <hip/hip_runtime.h>

#define NP 8732
#define NQ (NP / 4)          // 2183 float4 chunks
#define NPT 35               // ceil(NP / 256) per-thread CE registers
#define NO 16
#define BLK 256
#define NWAVE (BLK / 64)
#define SPLIT 4
#define CHUNK (NP / SPLIT)   // 2183 exactly

// ---------------------------------------------------------------------------
// Evidence log:
//  - One block/row is grid-limited to 2 blocks/CU (21% occupancy): latency
//    stalls dominate. Match phase split out at grid B*SPLIT fixed its half.
//  - BLK=512 regressed (barrier pile-up); launch_bounds cap below need
//    spills to scratch (52MB writes, 2.3x slower) -- watch WRITE_SIZE.
//  - 16-object reg cache (75+ regs vs per-wave budget heuristics) got parked
//    in AGPRs twice (VGPR_Count 104/56, v_accvgpr per access). 8-object was
//    marginal; round 7 uses 4 objects/thread (~50 VGPRs) + (256,8) so the
//    cache is VGPR-resident at 8 waves/SIMD.
//  - Ballot-aggregated histograms cost more VALU than conflicts saved.
//  - Phase D: register-resident CE + 4096-bin select w/ early exit.
// ---------------------------------------------------------------------------

// Kernel A: match a CHUNK of priors vs all 16 objects. Lane quads own 4
// objects each; 64 priors per block-iteration.
__global__ __launch_bounds__(BLK, 8) void match_kernel(
    const float* __restrict__ boxes,    // [B,O,4] cxcy
    const float* __restrict__ priors,   // [P,4]  cxcy
    unsigned char* __restrict__ g_obj,  // [B,NP]
    float* __restrict__ g_bv,           // [B,16,SPLIT]
    int*   __restrict__ g_bi)           // [B,16,SPLIT]
{
    const int b    = blockIdx.x;
    const int s    = blockIdx.y;
    const int tid  = threadIdx.x;
    const int lane = tid & 63;
    const int wv   = tid >> 6;
    const int quad = tid & 3;            // object group: 4*quad .. 4*quad+3
    const int objLo = quad << 2;
    const int lo = s * CHUNK, hi = lo + CHUNK;

    __shared__ float s_bxy[NO][4];
    __shared__ float s_barea[NO];
    __shared__ float s_redv[NO * NWAVE];
    __shared__ int   s_redi[NO * NWAVE];

    if (tid < NO) {
        const float* bx = boxes + (size_t)b * NO * 4 + tid * 4;
        float cx = bx[0], cy = bx[1], w = bx[2], h = bx[3];
        s_bxy[tid][0] = cx - w * 0.5f; s_bxy[tid][1] = cy - h * 0.5f;
        s_bxy[tid][2] = cx + w * 0.5f; s_bxy[tid][3] = cy + h * 0.5f;
        s_barea[tid] = w * h;
    }
    __syncthreads();

    // register-cache this thread's 4 objects (20 VGPRs)
    float rx0[4], ry0[4], rx1[4], ry1[4], ra[4];
#pragma unroll
    for (int j = 0; j < 4; j++) {
        rx0[j] = s_bxy[objLo + j][0]; ry0[j] = s_bxy[objLo + j][1];
        rx1[j] = s_bxy[objLo + j][2]; ry1[j] = s_bxy[objLo + j][3];
        ra[j]  = s_barea[objLo + j];
    }

    float tbv[4]; int tbp[4];
#pragma unroll
    for (int j = 0; j < 4; j++) { tbv[j] = -1.0f; tbp[j] = lo; }

    unsigned char* obj_row = g_obj + (size_t)b * NP;
    for (int p = lo + (tid >> 2); p < hi; p += (BLK / 4)) {
        float4 pr = ((const float4*)priors)[p];
        float px0 = pr.x - pr.z * 0.5f, py0 = pr.y - pr.w * 0.5f;
        float px1 = pr.x + pr.z * 0.5f, py1 = pr.y + pr.w * 0.5f;
        float areab = pr.z * pr.w;
        float bv = -1.0f; int bo = objLo;
#pragma unroll
        for (int j = 0; j < 4; j++) {
            float ix0 = fmaxf(rx0[j], px0);
            float iy0 = fmaxf(ry0[j], py0);
            float ix1 = fminf(rx1[j], px1);
            float iy1 = fminf(ry1[j], py1);
            float iw = fmaxf(ix1 - ix0, 0.0f);
            float ih = fmaxf(iy1 - iy0, 0.0f);
            float inter = iw * ih;
            float den = ra[j] + areab - inter;
            float iou = inter * __builtin_amdgcn_rcpf(den);
            if (iou > bv)     { bv = iou; bo = objLo + j; }   // first-wins over o
            if (iou > tbv[j]) { tbv[j] = iou; tbp[j] = p; }   // first-wins over p
        }
        // combine across the quad; lower lane = lower object indices wins ties
        float vN = __shfl_xor(bv, 1, 64);
        int   oN = __shfl_xor(bo, 1, 64);
        bool take = (quad & 1) ? (vN >= bv) : (vN > bv);
        if (take) { bv = vN; bo = oN; }
        vN = __shfl_xor(bv, 2, 64);
        oN = __shfl_xor(bo, 2, 64);
        take = (quad & 2) ? (vN >= bv) : (vN > bv);
        if (take) { bv = vN; bo = oN; }
        if (quad == 0) {
            bool pos = (bv >= 0.5f);
            obj_row[p] = (unsigned char)(bo | (pos ? 0x80 : 0));
        }
    }

    // per-object block reduction (strides multiples of 4 keep quad classes
    // disjoint; within a wave lower lane = lower prior, so prefer-smaller-idx
    // tie rule preserves first-wins)
#pragma unroll
    for (int j = 0; j < 4; j++) {
        float v = tbv[j]; int i = tbp[j];
        for (int off = 32; off >= 4; off >>= 1) {
            float v2 = __shfl_down(v, off, 64);
            int   i2 = __shfl_down(i, off, 64);
            if (v2 > v || (v2 == v && i2 < i)) { v = v2; i = i2; }
        }
        if (lane < 4) {   // lane q holds objects 4q..4q+3
            s_redv[(objLo + j) * NWAVE + wv] = v;
            s_redi[(objLo + j) * NWAVE + wv] = i;
        }
    }
    __syncthreads();
    if (tid < NO) {
        float v = s_redv[tid * NWAVE]; int i = s_redi[tid * NWAVE];
#pragma unroll
        for (int w = 1; w < NWAVE; w++) {
            float v2 = s_redv[tid * NWAVE + w]; int i2 = s_redi[tid * NWAVE + w];
            if (v2 > v || (v2 == v && i2 < i)) { v = v2; i = i2; }
        }
        g_bv[((size_t)b * NO + tid) * SPLIT + s] = v;
        g_bi[((size_t)b * NO + tid) * SPLIT + s] = i;
    }
}

// Histogram bin selection over 4096 bins: find bin holding the kk-th largest
// (counting from the top); updates kk to the rank within the bin.
__device__ __forceinline__ int hist_select(unsigned* hist, unsigned* s_part,
                                           unsigned* s_csuf, unsigned* s_sel,
                                           unsigned& kk, int tid, int lane, int wv)
{
    unsigned ps = 0;
#pragma unroll
    for (int i = 0; i < 16; i++) ps += hist[tid * 16 + i];
    s_part[tid] = ps;
    __syncthreads();
    if (wv == 0) {
        unsigned c0 = s_part[4 * lane + 0], c1 = s_part[4 * lane + 1];
        unsigned c2 = s_part[4 * lane + 2], c3 = s_part[4 * lane + 3];
        unsigned g = c0 + c1 + c2 + c3;
        unsigned incl = g;
#pragma unroll
        for (int off = 1; off < 64; off <<= 1) {
            unsigned o = __shfl_down(incl, off, 64);
            if (lane + off < 64) incl += o;
        }
        unsigned excl = incl - g;           // count in chunks above this one
        s_csuf[4 * lane + 3] = excl;
        s_csuf[4 * lane + 2] = excl + c3;
        s_csuf[4 * lane + 1] = excl + c3 + c2;
        s_csuf[4 * lane + 0] = excl + c3 + c2 + c1;
    }
    __syncthreads();
    unsigned base = s_csuf[tid];            // count in bins >= 16*(tid+1)
    if (base < kk && kk <= base + s_part[tid]) {   // exactly one thread
        unsigned run = base;
        for (int i = 15; i >= 0; i--) {
            unsigned h = hist[tid * 16 + i];
            if (kk <= run + h) { s_sel[0] = (unsigned)(tid * 16 + i); s_sel[1] = kk - run; break; }
            run += h;
        }
    }
    __syncthreads();
    kk = s_sel[1];
    return (int)s_sel[0];
}

// Kernel B: per-row losses. CE values live in per-thread registers; padding
// slots hold 0.0f which is provably inert in the top-K sum formula.
__global__ __launch_bounds__(BLK, 2) void loss_kernel(
    const float* __restrict__ plocs,    // [B,P,4]
    const float* __restrict__ pscores,  // [B,P,2]
    const float* __restrict__ boxes,    // [B,O,4]
    const float* __restrict__ priors,   // [P,4]
    const unsigned char* __restrict__ g_obj,
    const float* __restrict__ g_bv,
    const int*   __restrict__ g_bi,
    float* __restrict__ loc_out,
    float* __restrict__ conf_out,
    int*   __restrict__ npos_out)
{
    const int b    = blockIdx.x;
    const int tid  = threadIdx.x;
    const int lane = tid & 63;
    const int wv   = tid >> 6;

    __shared__ unsigned char s_obj[NP];
    __shared__ unsigned s_hist[4096];
    __shared__ unsigned s_part[256];
    __shared__ unsigned s_csuf[256];
    __shared__ unsigned s_sel[2];
    __shared__ float s_bcw[NO][4];
    __shared__ int   s_bestp[NO];
    __shared__ float s_tval;
    __shared__ float s_fred[3 * NWAVE];
    __shared__ int   s_ired[NWAVE];

    // load obj bytes (coalesced as words) + boxes; reduce forced candidates
    const unsigned* objw = (const unsigned*)(g_obj + (size_t)b * NP);
    for (int i = tid; i < NP / 4; i += BLK) ((unsigned*)s_obj)[i] = objw[i];
    if (tid < NO * 4) ((float*)s_bcw)[tid] = boxes[(size_t)b * NO * 4 + tid];
    if (tid < NO) {
        // splits cover ascending p ranges; prefer-larger, then smaller idx
        const float* bv = g_bv + ((size_t)b * NO + tid) * SPLIT;
        const int*   bi = g_bi + ((size_t)b * NO + tid) * SPLIT;
        float v = bv[0]; int i = bi[0];
#pragma unroll
        for (int s = 1; s < SPLIT; s++) {
            float v2 = bv[s]; int i2 = bi[s];
            if (v2 > v || (v2 == v && i2 < i)) { v = v2; i = i2; }
        }
        s_bestp[tid] = i;
    }
    __syncthreads();
    if (tid == 0) {   // serial ascending: last o wins on duplicate priors
#pragma unroll
        for (int o = 0; o < NO; o++) s_obj[s_bestp[o]] = (unsigned char)(0x80 | o);
    }
    __syncthreads();

    // CE for all priors (into registers), loc L1 for positives
    float ce[NPT];
    float loc_sum = 0.0f, conf_pos = 0.0f; int np = 0;
    const float2* sc2 = (const float2*)(pscores + (size_t)b * NP * 2);
    const float4* pl4 = (const float4*)(plocs  + (size_t)b * NP * 4);
#pragma unroll
    for (int k = 0; k < NPT; k++) {
        int p = tid + k * BLK;
        float v = 0.0f;
        if (p < NP) {
            unsigned m = s_obj[p];
            bool pos = (m & 0x80) != 0;
            float2 s = sc2[p];
            float mx = fmaxf(s.x, s.y);
            float dd = fabsf(s.x - s.y);
            float cev = mx + __logf(1.0f + __expf(-dd)) - (pos ? s.y : s.x);
            if (pos) {
                np++;
                conf_pos += cev;
                int o = m & 15;
                float4 pr = ((const float4*)priors)[p];
                float gx = (s_bcw[o][0] - pr.x) / (pr.z / 10.0f);
                float gy = (s_bcw[o][1] - pr.y) / (pr.w / 10.0f);
                float gw = __logf(s_bcw[o][2] / pr.z) * 5.0f;
                float gh = __logf(s_bcw[o][3] / pr.w) * 5.0f;
                float4 pl = pl4[p];
                loc_sum += fabsf(pl.x - gx) + fabsf(pl.y - gy)
                         + fabsf(pl.z - gw) + fabsf(pl.w - gh);
            } else {
                v = cev;
            }
        }
        ce[k] = v;
    }

    int npw = np;
    for (int off = 32; off; off >>= 1) npw += __shfl_down(npw, off, 64);
    if (lane == 0) s_ired[wv] = npw;
    __syncthreads();
    int n_pos = 0;
#pragma unroll
    for (int w = 0; w < NWAVE; w++) n_pos += s_ired[w];

    // select K-th largest CE: up to 3 histogram levels over bits [30:19],
    // [18:7], [6:0]; early exit when the selected bin is unique.
    const int K = 3 * n_pos;
    const bool selAll = (K >= NP);
    float t = 0.0f;
    if (!selAll) {
        unsigned kk = (unsigned)K;
        // level 1
        for (int i = tid; i < 4096; i += BLK) s_hist[i] = 0u;
        __syncthreads();
#pragma unroll
        for (int k = 0; k < NPT; k++)
            atomicAdd(&s_hist[__float_as_uint(ce[k]) >> 19], 1u);
        __syncthreads();
        unsigned b1 = (unsigned)hist_select(s_hist, s_part, s_csuf, s_sel, kk, tid, lane, wv);
        unsigned cnt1 = s_hist[b1];
        if (cnt1 == 1u) {
#pragma unroll
            for (int k = 0; k < NPT; k++)
                if ((__float_as_uint(ce[k]) >> 19) == b1) s_tval = ce[k];
            __syncthreads();
            t = s_tval;
        } else {
            // level 2
            __syncthreads();
            for (int i = tid; i < 4096; i += BLK) s_hist[i] = 0u;
            __syncthreads();
#pragma unroll
            for (int k = 0; k < NPT; k++) {
                unsigned u = __float_as_uint(ce[k]);
                if ((u >> 19) == b1) atomicAdd(&s_hist[(u >> 7) & 0xFFFu], 1u);
            }
            __syncthreads();
            unsigned b2 = (unsigned)hist_select(s_hist, s_part, s_csuf, s_sel, kk, tid, lane, wv);
            unsigned p2 = (b1 << 12) | b2;
            unsigned cnt2 = s_hist[b2];
            if (cnt2 == 1u) {
#pragma unroll
                for (int k = 0; k < NPT; k++)
                    if ((__float_as_uint(ce[k]) >> 7) == p2) s_tval = ce[k];
                __syncthreads();
                t = s_tval;
            } else {
                // level 3
                __syncthreads();
                for (int i = tid; i < 4096; i += BLK) s_hist[i] = 0u;
                __syncthreads();
#pragma unroll
                for (int k = 0; k < NPT; k++) {
                    unsigned u = __float_as_uint(ce[k]);
                    if ((u >> 7) == p2) atomicAdd(&s_hist[u & 0x7Fu], 1u);
                }
                __syncthreads();
                unsigned b3 = (unsigned)hist_select(s_hist, s_part, s_csuf, s_sel, kk, tid, lane, wv);
                t = __uint_as_float((p2 << 7) | b3);
            }
        }
    }

    // sum of top-K = sum(v > t) + (K - cnt_gt) * t  (exact under ties; the
    // padded zeros never pass v > t and contribute 0 in the selAll branch)
    float sgt = 0.0f; int cgt = 0;
#pragma unroll
    for (int k = 0; k < NPT; k++) {
        float v = ce[k];
        if (selAll || v > t) { sgt += v; cgt++; }
    }

    float a = sgt, c = conf_pos, l = loc_sum; int g = cgt;
    for (int off = 32; off; off >>= 1) {
        a += __shfl_down(a, off, 64);
        c += __shfl_down(c, off, 64);
        l += __shfl_down(l, off, 64);
        g += __shfl_down(g, off, 64);
    }
    __syncthreads();
    if (lane == 0) {
        s_fred[wv] = a; s_fred[NWAVE + wv] = c; s_fred[2 * NWAVE + wv] = l;
        s_ired[wv] = g;
    }
    __syncthreads();
    if (tid == 0) {
        float sa = 0.0f, sc = 0.0f, sl = 0.0f; int sg = 0;
#pragma unroll
        for (int w = 0; w < NWAVE; w++) {
            sa += s_fred[w]; sc += s_fred[NWAVE + w]; sl += s_fred[2 * NWAVE + w];
            sg += s_ired[w];
        }
        float conf_hn = selAll ? sa : (sa + (float)(K - sg) * t);
        conf_out[b] = sc + conf_hn;
        loc_out[b]  = sl;
        npos_out[b] = n_pos;
    }
}

// ------------------------- round-5 monolith (fallback if ws too small) -----
__global__ __launch_bounds__(BLK, 2) void mbox_row_kernel(
    const float* __restrict__ plocs, const float* __restrict__ pscores,
    const float* __restrict__ boxes, const float* __restrict__ priors,
    float* __restrict__ loc_out, float* __restrict__ conf_out,
    int* __restrict__ npos_out)
{
    const int b = blockIdx.x, tid = threadIdx.x, lane = tid & 63, wv = tid >> 6;
    const int par = tid & 1, objLo = par << 3;
    __shared__ __align__(16) float s_ce[NP];
    __shared__ unsigned char s_obj[NP];
    __shared__ float s_bcw[NO][4], s_bxy[NO][4], s_barea[NO];
    __shared__ float s_redv[NO * NWAVE]; __shared__ int s_redi[NO * NWAVE];
    __shared__ int s_bestp[NO];
    __shared__ unsigned s_hist16[16];
    __shared__ float s_tval;
    __shared__ float s_fred[3 * NWAVE]; __shared__ int s_ired[NWAVE];

    if (tid < NO * 4) ((float*)s_bcw)[tid] = boxes[(size_t)b * NO * 4 + tid];
    __syncthreads();
    if (tid < NO) {
        float cx = s_bcw[tid][0], cy = s_bcw[tid][1], w = s_bcw[tid][2], h = s_bcw[tid][3];
        s_bxy[tid][0] = cx - w * 0.5f; s_bxy[tid][1] = cy - h * 0.5f;
        s_bxy[tid][2] = cx + w * 0.5f; s_bxy[tid][3] = cy + h * 0.5f;
        s_barea[tid] = w * h;
    }
    __syncthreads();
    float rx0[8], ry0[8], rx1[8], ry1[8], ra[8];
#pragma unroll
    for (int j = 0; j < 8; j++) {
        rx0[j] = s_bxy[objLo + j][0]; ry0[j] = s_bxy[objLo + j][1];
        rx1[j] = s_bxy[objLo + j][2]; ry1[j] = s_bxy[objLo + j][3];
        ra[j]  = s_barea[objLo + j];
    }
    float tbv[8]; int tbp[8];
#pragma unroll
    for (int j = 0; j < 8; j++) { tbv[j] = -1.0f; tbp[j] = 0; }
    for (int p = (tid >> 1); p < NP; p += (BLK / 2)) {
        float4 pr = ((const float4*)priors)[p];
        float px0 = pr.x - pr.z * 0.5f, py0 = pr.y - pr.w * 0.5f;
        float px1 = pr.x + pr.z * 0.5f, py1 = pr.y + pr.w * 0.5f;
        float areab = pr.z * pr.w;
        float bv = -1.0f; int bo = objLo;
#pragma unroll
        for (int j = 0; j < 8; j++) {
            float ix0 = fmaxf(rx0[j], px0), iy0 = fmaxf(ry0[j], py0);
            float ix1 = fminf(rx1[j], px1), iy1 = fminf(ry1[j], py1);
            float iw = fmaxf(ix1 - ix0, 0.0f), ih = fmaxf(iy1 - iy0, 0.0f);
            float inter = iw * ih, den = ra[j] + areab - inter;
            float iou = inter * __builtin_amdgcn_rcpf(den);
            if (iou > bv) { bv = iou; bo = objLo + j; }
            if (iou > tbv[j]) { tbv[j] = iou; tbp[j] = p; }
        }
        float vN = __shfl_xor(bv, 1, 64); int oN = __shfl_xor(bo, 1, 64);
        bool take = par ? (vN >= bv) : (vN > bv);
        if (take) { bv = vN; bo = oN; }
        if (par == 0) s_obj[p] = (unsigned char)(bo | ((bv >= 0.5f) ? 0x80 : 0));
    }
#pragma unroll
    for (int j = 0; j < 8; j++) {
        float v = tbv[j]; int i = tbp[j];
        for (int off = 32; off >= 2; off >>= 1) {
            float v2 = __shfl_down(v, off, 64); int i2 = __shfl_down(i, off, 64);
            if (v2 > v || (v2 == v && i2 < i)) { v = v2; i = i2; }
        }
        if (lane < 2) { s_redv[(objLo + j) * NWAVE + wv] = v; s_redi[(objLo + j) * NWAVE + wv] = i; }
    }
    __syncthreads();
    if (tid < NO) {
        float v = s_redv[tid * NWAVE]; int i = s_redi[tid * NWAVE];
#pragma unroll
        for (int w = 1; w < NWAVE; w++) {
            float v2 = s_redv[tid * NWAVE + w]; int i2 = s_redi[tid * NWAVE + w];
            if (v2 > v || (v2 == v && i2 < i)) { v = v2; i = i2; }
        }
        s_bestp[tid] = i;
    }
    __syncthreads();
    if (tid == 0) {
#pragma unroll
        for (int o = 0; o < NO; o++) s_obj[s_bestp[o]] = (unsigned char)(0x80 | o);
    }
    __syncthreads();
    float loc_sum = 0.0f, conf_pos = 0.0f; int np = 0;
    const float2* sc2 = (const float2*)(pscores + (size_t)b * NP * 2);
    const float4* pl4 = (const float4*)(plocs + (size_t)b * NP * 4);
    for (int p = tid; p < NP; p += BLK) {
        unsigned m = s_obj[p]; bool pos = (m & 0x80) != 0;
        float2 s = sc2[p];
        float mx = fmaxf(s.x, s.y), dd = fabsf(s.x - s.y);
        float cev = mx + __logf(1.0f + __expf(-dd)) - (pos ? s.y : s.x);
        if (pos) {
            np++; conf_pos += cev;
            int o = m & 15;
            float4 pr = ((const float4*)priors)[p];
            float gx = (s_bcw[o][0] - pr.x) / (pr.z / 10.0f);
            float gy = (s_bcw[o][1] - pr.y) / (pr.w / 10.0f);
            float gw = __logf(s_bcw[o][2] / pr.z) * 5.0f;
            float gh = __logf(s_bcw[o][3] / pr.w) * 5.0f;
            float4 pl = pl4[p];
            loc_sum += fabsf(pl.x - gx) + fabsf(pl.y - gy) + fabsf(pl.z - gw) + fabsf(pl.w - gh);
            s_ce[p] = 0.0f;
        } else s_ce[p] = cev;
    }
    int npw = np;
    for (int off = 32; off; off >>= 1) npw += __shfl_down(npw, off, 64);
    if (lane == 0) s_ired[wv] = npw;
    __syncthreads();
    int n_pos = 0;
#pragma unroll
    for (int w = 0; w < NWAVE; w++) n_pos += s_ired[w];
    const int K = 3 * n_pos; const bool selAll = (K >= NP);
    float t = 0.0f;
    const float4* ce4 = (const float4*)s_ce;
    if (!selAll) {
        unsigned prefix = 0u, kk = (unsigned)K; bool done = false;
        for (int shift = 28; shift >= 0 && !done; shift -= 4) {
            __syncthreads();
            if (tid < 16) s_hist16[tid] = 0u;
            __syncthreads();
            unsigned maskhi = (shift == 28) ? 0u : (0xFFFFFFFFu << (shift + 4));
            for (int q = tid; q < NQ; q += BLK) {
                float4 v = ce4[q];
#pragma unroll
                for (int j = 0; j < 4; j++) {
                    unsigned u = __float_as_uint(j == 0 ? v.x : j == 1 ? v.y : j == 2 ? v.z : v.w);
                    if ((u & maskhi) == prefix) atomicAdd(&s_hist16[(u >> shift) & 15u], 1u);
                }
            }
            __syncthreads();
            int dsel = 15; unsigned cnt;
            for (;; dsel--) { cnt = s_hist16[dsel]; if (kk <= cnt || dsel == 0) break; kk -= cnt; }
            prefix |= ((unsigned)dsel << shift);
            if (shift > 0 && cnt == 1u) {
                unsigned mh = 0xFFFFFFFFu << shift;
                for (int q = tid; q < NQ; q += BLK) {
                    float4 v = ce4[q];
#pragma unroll
                    for (int j = 0; j < 4; j++) {
                        float f = (j == 0 ? v.x : j == 1 ? v.y : j == 2 ? v.z : v.w);
                        if ((__float_as_uint(f) & mh) == prefix) s_tval = f;
                    }
                }
                __syncthreads();
                t = s_tval; done = true;
            } else if (shift == 0) t = __uint_as_float(prefix);
        }
    }
    float sgt = 0.0f; int cgt = 0;
    for (int q = tid; q < NQ; q += BLK) {
        float4 v = ce4[q];
        if (selAll || v.x > t) { sgt += v.x; cgt++; }
        if (selAll || v.y > t) { sgt += v.y; cgt++; }
        if (selAll || v.z > t) { sgt += v.z; cgt++; }
        if (selAll || v.w > t) { sgt += v.w; cgt++; }
    }
    float a = sgt, c = conf_pos, l = loc_sum; int g = cgt;
    for (int off = 32; off; off >>= 1) {
        a += __shfl_down(a, off, 64); c += __shfl_down(c, off, 64);
        l += __shfl_down(l, off, 64); g += __shfl_down(g, off, 64);
    }
    __syncthreads();
    if (lane == 0) { s_fred[wv] = a; s_fred[NWAVE + wv] = c; s_fred[2 * NWAVE + wv] = l; s_ired[wv] = g; }
    __syncthreads();
    if (tid == 0) {
        float sa = 0, sc = 0, sl = 0; int sg = 0;
#pragma unroll
        for (int w = 0; w < NWAVE; w++) { sa += s_fred[w]; sc += s_fred[NWAVE + w]; sl += s_fred[2 * NWAVE + w]; sg += s_ired[w]; }
        float conf_hn = selAll ? sa : (sa + (float)(K - sg) * t);
        conf_out[b] = sc + conf_hn; loc_out[b] = sl; npos_out[b] = n_pos;
    }
}

__global__ __launch_bounds__(256) void mbox_finalize_kernel(
    const float* __restrict__ loc_in, const float* __restrict__ conf_in,
    const int* __restrict__ npos_in, int B, float* __restrict__ out)
{
    __shared__ float sl[4], sc[4];
    __shared__ int si[4];
    int tid = threadIdx.x, lane = tid & 63, wv = tid >> 6;
    float l = 0.0f, c = 0.0f; int n = 0;
    for (int i = tid; i < B; i += 256) { l += loc_in[i]; c += conf_in[i]; n += npos_in[i]; }
    for (int off = 32; off; off >>= 1) {
        l += __shfl_down(l, off, 64);
        c += __shfl_down(c, off, 64);
        n += __shfl_down(n, off, 64);
    }
    if (lane == 0) { sl[wv] = l; sc[wv] = c; si[wv] = n; }
    __syncthreads();
    if (tid == 0) {
        float tl = sl[0] + sl[1] + sl[2] + sl[3];
        float tc = sc[0] + sc[1] + sc[2] + sc[3];
        int tn = si[0] + si[1] + si[2] + si[3];
        float fn = (float)tn;
        out[0] = tc / fn + tl / (fn * 4.0f);
    }
}

extern "C" void kernel_launch(void* const* d_in, const int* in_sizes, int n_in,
                              void* d_out, int out_size, void* d_ws, size_t ws_size,
                              hipStream_t stream) {
    const float* plocs   = (const float*)d_in[0];
    const float* pscores = (const float*)d_in[1];
    const float* boxes   = (const float*)d_in[2];
    const float* priors  = (const float*)d_in[3];
    const int B = in_sizes[0] / (NP * 4);

    float* loc_ws  = (float*)d_ws;
    float* conf_ws = loc_ws + B;
    int*   np_ws   = (int*)(conf_ws + B);
    float* g_bv    = (float*)(np_ws + B);
    int*   g_bi    = (int*)(g_bv + (size_t)B * NO * SPLIT);
    unsigned char* g_obj = (unsigned char*)(g_bi + (size_t)B * NO * SPLIT);
    size_t need = (size_t)(3 * B) * 4 + (size_t)B * NO * SPLIT * 8 + (size_t)B * NP;

    if (ws_size >= need) {
        match_kernel<<<dim3(B, SPLIT), BLK, 0, stream>>>(boxes, priors, g_obj, g_bv, g_bi);
        loss_kernel<<<B, BLK, 0, stream>>>(plocs, pscores, boxes, priors,
                                           g_obj, g_bv, g_bi, loc_ws, conf_ws, np_ws);
    } else {
        mbox_row_kernel<<<B, BLK, 0, stream>>>(plocs, pscores, boxes, priors,
                                               loc_ws, conf_ws, np_ws);
    }
    mbox_finalize_kernel<<<1, 256, 0, stream>>>(loc_ws, conf_ws, np_ws, B, (float*)d_out);
}